// Round 3
// baseline (477.571 us; speedup 1.0000x reference)
//
#include <hip/hip_runtime.h>
#include <cstdint>
#include <cstddef>

#define DEVINL __device__ __forceinline__

typedef __bf16 bf16x8 __attribute__((ext_vector_type(8)));
typedef float f32x4 __attribute__((ext_vector_type(4)));

static constexpr int NN = 10000;     // nodes
static constexpr int NE = 80000;     // edges
static constexpr int IN_DIM = 1024;
static constexpr int HID = 4096;
static constexpr int OUTD = 256;
static constexpr int M_PAD = 10112;  // 79*128 (also 158*64)

// fp32 -> bf16 round-nearest-even
DEVINL unsigned short f2bf(float f) {
  unsigned int u = __builtin_bit_cast(unsigned int, f);
  u += 0x7fffu + ((u >> 16) & 1u);
  return (unsigned short)(u >> 16);
}
DEVINL float bf2f(unsigned short h) {
  unsigned int u = ((unsigned int)h) << 16;
  return __builtin_bit_cast(float, u);
}

// async global->LDS, 16B per lane; LDS dest is wave-uniform base + lane*16
DEVINL void ld_lds16(const void* g, void* l) {
  __builtin_amdgcn_global_load_lds(
      (const __attribute__((address_space(1))) unsigned int*)g,
      (__attribute__((address_space(3))) unsigned int*)l, 16, 0, 0);
}

// ---------------- fused prep: conv_w1 + conv_w2 + x->bf16 + degree count ----------------
static constexpr int PREP_B1 = 8192;
static constexpr int PREP_B2 = PREP_B1 + 2048;
static constexpr int PREP_B3 = PREP_B2 + 10000;
static constexpr int PREP_NB = PREP_B3 + 313;

__global__ __launch_bounds__(256) void prep_kernel(
    const float* __restrict__ W1l, const float* __restrict__ W1r,
    const float* __restrict__ W2l, const float* __restrict__ W2r,
    const float* __restrict__ x, const int* __restrict__ dst,
    unsigned short* __restrict__ w1cat, unsigned short* __restrict__ w2cat,
    unsigned short* __restrict__ x_bf, int* __restrict__ deg) {
  int b = blockIdx.x;
  int t = threadIdx.x;
  if (b < PREP_B1) {  // w1cat [4096][2048]: row n = [W1_l row n | W1_r row n]
    int g = b * 256 + t;
    int n = g >> 9;
    int kg = g & 511;
    const float* s = (kg < 256) ? (W1l + (size_t)n * 1024 + kg * 4)
                                : (W1r + (size_t)n * 1024 + (kg - 256) * 4);
    float4 v = *(const float4*)s;
    ushort4 p = {f2bf(v.x), f2bf(v.y), f2bf(v.z), f2bf(v.w)};
    ((ushort4*)w1cat)[g] = p;
  } else if (b < PREP_B2) {  // w2cat [512][4096]: rows 0..255 = W2_l, 256..511 = W2_r
    int g = (b - PREP_B1) * 256 + t;
    int n = g >> 10;
    int kg = g & 1023;
    const float* s = (n < 256) ? (W2l + (size_t)n * 4096 + kg * 4)
                               : (W2r + (size_t)(n - 256) * 4096 + kg * 4);
    float4 v = *(const float4*)s;
    ushort4 p = {f2bf(v.x), f2bf(v.y), f2bf(v.z), f2bf(v.w)};
    ((ushort4*)w2cat)[g] = p;
  } else if (b < PREP_B3) {  // x -> bf16, [10000][1024]
    int g = (b - PREP_B2) * 256 + t;
    int i = g >> 8;
    int kg = g & 255;
    float4 v = ((const float4*)(x + (size_t)i * IN_DIM))[kg];
    ushort4 p = {f2bf(v.x), f2bf(v.y), f2bf(v.z), f2bf(v.w)};
    ((ushort4*)(x_bf + (size_t)i * IN_DIM))[kg] = p;
  } else {  // degree count
    int e = (b - PREP_B3) * 256 + t;
    if (e < NE) atomicAdd(&deg[dst[e]], 1);
  }
}

// one-block exclusive scan over NN degrees -> offs[0..NN] and cursor copy cur[]
__global__ __launch_bounds__(1024) void scan_kernel(const int* __restrict__ deg,
                                                    int* __restrict__ offs,
                                                    int* __restrict__ cur) {
  __shared__ int part[1024];
  constexpr int NPT = 10;  // 1024*10 = 10240 >= NN
  int t = threadIdx.x;
  int base = t * NPT;
  int s = 0;
  for (int j = 0; j < NPT; ++j) {
    int n = base + j;
    s += (n < NN) ? deg[n] : 0;
  }
  part[t] = s;
  __syncthreads();
  for (int o = 1; o < 1024; o <<= 1) {  // Hillis-Steele inclusive scan
    int v = (t >= o) ? part[t - o] : 0;
    __syncthreads();
    part[t] += v;
    __syncthreads();
  }
  int pre = (t > 0) ? part[t - 1] : 0;
  for (int j = 0; j < NPT; ++j) {
    int n = base + j;
    if (n < NN) {
      offs[n] = pre;
      cur[n] = pre;
      pre += deg[n];
    }
  }
  if (t == 1023) offs[NN] = part[1023];  // == NE
}

// bin edges: csr[cur[dst]++] = src  (cur pre-seeded with offs by scan)
__global__ void bin_kernel(const int* __restrict__ src, const int* __restrict__ dst,
                           int* __restrict__ cur, int* __restrict__ csr) {
  int e = blockIdx.x * 256 + threadIdx.x;
  if (e < NE) {
    int p = atomicAdd(&cur[dst[e]], 1);
    csr[p] = src[e];
  }
}

// ---------------- layer-1 gather (bf16 source): A1 = mean_agg(x) only ----------------
// GEMM1 reads x_bf directly for the K>=1024 half, so no x copy here.
// grid = M_PAD blocks; blocks >= NN zero the A1 AND x_bf pad rows.
__global__ __launch_bounds__(256) void gather1_kernel(unsigned short* __restrict__ x_bf,
                                                      const int* __restrict__ offs,
                                                      const int* __restrict__ csr,
                                                      unsigned short* __restrict__ A1) {
  int i = blockIdx.x;
  int t = threadIdx.x;  // 256 threads x ushort4 = 1024 bf16 = one row
  unsigned short* row = A1 + (size_t)i * 1024;
  if (i >= NN) {
    ushort4 z = {0, 0, 0, 0};
    ((ushort4*)row)[t] = z;
    ((ushort4*)(x_bf + (size_t)i * 1024))[t] = z;
    return;
  }
  int beg = offs[i], end = offs[i + 1];
  float4 a0 = {0.f, 0.f, 0.f, 0.f}, a1 = {0.f, 0.f, 0.f, 0.f};
  int j = beg;
  for (; j + 2 <= end; j += 2) {
    int s0 = __builtin_amdgcn_readfirstlane(csr[j]);
    int s1 = __builtin_amdgcn_readfirstlane(csr[j + 1]);
    ushort4 u0 = ((const ushort4*)(x_bf + (size_t)s0 * IN_DIM))[t];
    ushort4 u1 = ((const ushort4*)(x_bf + (size_t)s1 * IN_DIM))[t];
    a0.x += bf2f(u0.x); a0.y += bf2f(u0.y); a0.z += bf2f(u0.z); a0.w += bf2f(u0.w);
    a1.x += bf2f(u1.x); a1.y += bf2f(u1.y); a1.z += bf2f(u1.z); a1.w += bf2f(u1.w);
  }
  if (j < end) {
    int s0 = __builtin_amdgcn_readfirstlane(csr[j]);
    ushort4 u0 = ((const ushort4*)(x_bf + (size_t)s0 * IN_DIM))[t];
    a0.x += bf2f(u0.x); a0.y += bf2f(u0.y); a0.z += bf2f(u0.z); a0.w += bf2f(u0.w);
  }
  float inv = 1.0f / (float)max(end - beg, 1);
  ushort4 pa = {f2bf((a0.x + a1.x) * inv), f2bf((a0.y + a1.y) * inv),
                f2bf((a0.z + a1.z) * inv), f2bf((a0.w + a1.w) * inv)};
  ((ushort4*)row)[t] = pa;
}

// ---------------- GEMM1: 256x256 tile, 8 waves, counted-vmcnt phased schedule ----------
// C[M_PAD,4096] = [A1 | x_bf] @ w1cat^T, relu(+bias), bf16 out.
// T3+T4: double-buffered K-tiles (BK=64), stage-ahead-1 issued BEFORE
// s_waitcnt vmcnt(8) -> next tile's 8 loads stay in flight across the barrier
// (never drains to 0 in the main loop). Raw s_barrier (no implicit waitcnt drain).
// T5: setprio(1) around each 16-MFMA quadrant phase (4 phases/K-tile).
// LDS chunk swizzle identical to the verified 128-tile kernel: physical 16B chunk
// slot of row r holds logical chunk slot^(r&7); read at p=(kk*4+quad)^(l16&7)
// (measured 0 bank conflicts). global_load_lds dest stays linear (rule #21).
// M=10112 not 256-divisible: source rows clamped to 10111 (zeroed pad row),
// C-writes guarded m<10112.
// Correctness of buffer reuse: stage into buf[p^1] at iter t is issued after
// iter t-1's final phase barrier, which post-dates every wave's lgkmcnt(0)
// (all reads of buf[p^1] landed in regs). Reads of tile t at iter t happen
// after vmcnt(8)+barrier (tile t's 8 oldest loads complete in every wave).
__global__ __launch_bounds__(512) void gemm1_8ph_kernel(
    const unsigned short* __restrict__ A,    // A1  (k < 1024), row stride 1024
    const unsigned short* __restrict__ A2,   // x_bf (k >= 1024), row stride 1024
    const unsigned short* __restrict__ Bt,   // w1cat [4096][2048]
    const float* __restrict__ bias,
    unsigned short* __restrict__ C) {
  constexpr int BM = 256, BN = 256, BK = 64;
  constexpr int K = 2048, N = 4096;
  constexpr int NT = K / BK;  // 32
  constexpr int NUMM = 40, NUMN = 16, GM = 8, NPG = GM * NUMN;

  __shared__ unsigned short Asm[2][BM * BK];  // 2 x 32 KiB
  __shared__ unsigned short Bsm[2][BN * BK];  // 2 x 32 KiB  (total 128 KiB)

  // grouped swizzle (m-fastest within GM band): B n-panel reused across 8 blocks
  const int pid = blockIdx.x;
  const int gid = pid / NPG;
  const int first_m = gid * GM;            // 40 = 5*8, bands exact
  const int local = pid % NPG;
  const int pm = first_m + (local % GM);
  const int pn = local / GM;
  const long tm0 = (long)pm * BM;
  const long tn0 = (long)pn * BN;

  const int tid = threadIdx.x;  // 0..511
  const int lane = tid & 63;
  const int wave = tid >> 6;    // 0..7
  const int quad = lane >> 4;
  const int l16 = lane & 15;
  const int l7 = l16 & 7;
  const int wr = wave >> 2;     // 0..1: A-half (rows wr*128..)
  const int wc = wave & 3;      // 0..3: B quarter (rows wc*64..)
  const int wm = wr * 128;
  const int wn = wc * 64;

  f32x4 acc[8][4];
#pragma unroll
  for (int i = 0; i < 8; ++i)
#pragma unroll
    for (int j = 0; j < 4; ++j) acc[i][j] = (f32x4){0.f, 0.f, 0.f, 0.f};

  // staging map: chunk c = s*512 + tid; tile row r = c>>3; physical slot = c&7;
  // source logical chunk g = slot ^ (r&7); LDS dest linear (wave-uniform + lane*16)
  size_t aOffE[4], bOffE[4];
#pragma unroll
  for (int s = 0; s < 4; ++s) {
    int c = s * 512 + tid;
    int r = c >> 3;
    int g = (c & 7) ^ (r & 7);
    long ra = tm0 + r;
    if (ra > M_PAD - 1) ra = M_PAD - 1;  // clamp into zeroed pad row
    aOffE[s] = (size_t)ra * 1024 + g * 8;
    bOffE[s] = (size_t)(tn0 + r) * K + g * 8;
  }

#define STAGE_A(kt, buf)                                                        \
  {                                                                             \
    const unsigned short* ab_ = ((kt) < NT / 2) ? A : A2;                       \
    const int ka_ = ((kt) & (NT / 2 - 1)) * BK;                                 \
    _Pragma("unroll") for (int s_ = 0; s_ < 4; ++s_)                            \
        ld_lds16(ab_ + aOffE[s_] + ka_, &Asm[(buf)][(s_ * 512 + wave * 64) * 8]); \
  }
#define STAGE_B(kt, buf)                                                        \
  {                                                                             \
    const int k0_ = (kt)*BK;                                                    \
    _Pragma("unroll") for (int s_ = 0; s_ < 4; ++s_)                            \
        ld_lds16(Bt + bOffE[s_] + k0_, &Bsm[(buf)][(s_ * 512 + wave * 64) * 8]); \
  }

  STAGE_A(0, 0)
  STAGE_B(0, 0)

  for (int kt = 0; kt < NT; ++kt) {
    const int buf = kt & 1;
    if (kt + 1 < NT) {
      STAGE_A(kt + 1, buf ^ 1)
      STAGE_B(kt + 1, buf ^ 1)
      asm volatile("s_waitcnt vmcnt(8)" ::: "memory");  // tile kt landed; 8 in flight
    } else {
      asm volatile("s_waitcnt vmcnt(0)" ::: "memory");
    }
    __builtin_amdgcn_s_barrier();  // raw barrier: no implicit vmcnt drain

    const unsigned short* As = Asm[buf];
    const unsigned short* Bs = Bsm[buf];

    // B fragments for the whole K-tile (held across the 4 quadrant phases)
    bf16x8 bv[2][4];
#pragma unroll
    for (int kk = 0; kk < 2; ++kk)
#pragma unroll
      for (int nj = 0; nj < 4; ++nj) {
        int rb = wn + nj * 16 + l16;
        int p = (kk * 4 + quad) ^ l7;
        bv[kk][nj] = *(const bf16x8*)(Bs + rb * BK + p * 8);
      }

#pragma unroll
    for (int q = 0; q < 4; ++q) {
      bf16x8 af[2][2];
#pragma unroll
      for (int kk = 0; kk < 2; ++kk)
#pragma unroll
        for (int i = 0; i < 2; ++i) {
          int ra = wm + (q * 2 + i) * 16 + l16;
          int p = (kk * 4 + quad) ^ l7;
          af[kk][i] = *(const bf16x8*)(As + ra * BK + p * 8);
        }
      __builtin_amdgcn_s_barrier();                      // align wave phases
      asm volatile("s_waitcnt lgkmcnt(0)" ::: "memory");  // frags in regs
      __builtin_amdgcn_s_setprio(1);
#pragma unroll
      for (int kk = 0; kk < 2; ++kk)
#pragma unroll
        for (int i = 0; i < 2; ++i)
#pragma unroll
          for (int nj = 0; nj < 4; ++nj)
            acc[q * 2 + i][nj] = __builtin_amdgcn_mfma_f32_16x16x32_bf16(
                af[kk][i], bv[kk][nj], acc[q * 2 + i][nj], 0, 0, 0);
      __builtin_amdgcn_s_setprio(0);
      __builtin_amdgcn_s_barrier();  // reads of this buf done before overwrite
    }
  }
#undef STAGE_A
#undef STAGE_B

  // epilogue: relu(acc + bias) -> bf16; C/D layout col = lane&15, row = quad*4 + reg
#pragma unroll
  for (int mi = 0; mi < 8; ++mi) {
    long m0 = tm0 + wm + mi * 16 + quad * 4;
#pragma unroll
    for (int nj = 0; nj < 4; ++nj) {
      int n = (int)tn0 + wn + nj * 16 + l16;
      float bvs = bias[n];
#pragma unroll
      for (int r = 0; r < 4; ++r) {
        long m = m0 + r;
        if (m < M_PAD) {
          float v = fmaxf(acc[mi][nj][r] + bvs, 0.0f);
          C[(size_t)m * N + n] = f2bf(v);
        }
      }
    }
  }
}

// ---------------- bf16 MFMA GEMM, templated (kept for GEMM2) ----------------
// C[M_PAD,N] = A[M_PAD,K] * Bt[N,K]^T. 4 waves; NWY waves along n.
// See prior-session notes; structure unchanged.
template <int BM, int BN, int BK, int K, int KSPLIT, int N, int NUMM, int NUMN, int GM,
          int EPI, int NWY, bool ASPLIT>
__global__ __launch_bounds__(256) void gemm_kernel(const unsigned short* __restrict__ A,
                                                   const unsigned short* __restrict__ A2,
                                                   const unsigned short* __restrict__ Bt,
                                                   const float* __restrict__ bias,
                                                   void* __restrict__ C0out) {
  constexpr int MGR = 4 / NWY;            // waves along m
  constexpr int MI = BM / 16 / MGR;       // 16-row tiles per wave
  constexpr int NI = 4;                   // 16-col tiles per wave (BN = NWY*64)
  constexpr int CPR = BK / 8;             // 16B chunks per LDS row
  constexpr int SA = BM * CPR / 256;      // staging rounds for A (256 thr x 16B)
  constexpr int SB = BN * CPR / 256;
  constexpr int KK = BK / 32;             // MFMA k-steps per tile
  constexpr int KS = K / KSPLIT;          // K range per split
  constexpr int AS = ASPLIT ? K / 2 : K;  // A row stride
  __shared__ unsigned short Asm[BM * BK];
  __shared__ unsigned short Bsm[BN * BK];

  // grouped swizzle on grid.x
  constexpr int NPG = GM * NUMN;
  const int pid = blockIdx.x;
  const int gid = pid / NPG;
  const int first_m = gid * GM;
  const int sz = (NUMM - first_m < GM) ? (NUMM - first_m) : GM;
  const int local = pid % NPG;
  const int pm = first_m + local % sz;
  const int pn = local / sz;
  const int koff = (KSPLIT > 1) ? (int)blockIdx.y * KS : 0;

  const int tid = threadIdx.x;
  const int lane = tid & 63;
  const int wave = tid >> 6;
  const int quad = lane >> 4;
  const int l16 = lane & 15;
  const int wm = (wave % MGR) * (BM / MGR);
  const int wn = (wave / MGR) * 64;
  const long tm0 = (long)pm * BM;
  const long tn0 = (long)pn * BN;

  f32x4 acc[MI][NI];
#pragma unroll
  for (int i = 0; i < MI; ++i)
#pragma unroll
    for (int j = 0; j < NI; ++j) acc[i][j] = (f32x4){0.f, 0.f, 0.f, 0.f};

  size_t aOff[SA];
  unsigned short* aDst[SA];
  const unsigned short* bSrc[SB];
  unsigned short* bDst[SB];
#pragma unroll
  for (int s = 0; s < SA; ++s) {
    int c = s * 256 + wave * 64 + lane;
    int r = c / CPR;
    int g = (c % CPR) ^ (r & 7);
    aOff[s] = (size_t)(tm0 + r) * AS + koff + g * 8;
    aDst[s] = Asm + s * 2048 + wave * 512;  // wave-uniform base
  }
#pragma unroll
  for (int s = 0; s < SB; ++s) {
    int c = s * 256 + wave * 64 + lane;
    int r = c / CPR;
    int g = (c % CPR) ^ (r & 7);
    bSrc[s] = Bt + (size_t)(tn0 + r) * K + koff + g * 8;
    bDst[s] = Bsm + s * 2048 + wave * 512;
  }

  const int l7 = l16 & 7;

  for (int k0 = 0; k0 < KS; k0 += BK) {
    const unsigned short* ab = (!ASPLIT || k0 < K / 2) ? A : A2;
    const int ka = ASPLIT ? (k0 & (K / 2 - 1)) : k0;
#pragma unroll
    for (int s = 0; s < SA; ++s) ld_lds16(ab + aOff[s] + ka, aDst[s]);
#pragma unroll
    for (int s = 0; s < SB; ++s) ld_lds16(bSrc[s] + k0, bDst[s]);
    __syncthreads();  // drains vmcnt -> LDS tiles complete

#pragma unroll
    for (int kk = 0; kk < KK; ++kk) {
      const int p = (kk * 4 + quad) ^ l7;  // physical chunk for this frag
      bf16x8 af[MI], bv[NI];
#pragma unroll
      for (int i = 0; i < MI; ++i) {
        int ra = wm + i * 16 + l16;
        af[i] = *(const bf16x8*)(Asm + ra * BK + p * 8);
      }
#pragma unroll
      for (int j = 0; j < NI; ++j) {
        int rb = wn + j * 16 + l16;
        bv[j] = *(const bf16x8*)(Bsm + rb * BK + p * 8);
      }
#pragma unroll
      for (int i = 0; i < MI; ++i)
#pragma unroll
        for (int j = 0; j < NI; ++j)
          acc[i][j] = __builtin_amdgcn_mfma_f32_16x16x32_bf16(af[i], bv[j], acc[i][j], 0, 0, 0);
    }
    __syncthreads();  // LDS reads done before next stage overwrites
  }

  // epilogue: C/D layout col = lane&15, row = quad*4 + reg
  if (EPI == 1) {
    unsigned short* C = (unsigned short*)C0out;
#pragma unroll
    for (int i = 0; i < MI; ++i) {
      long m0 = tm0 + wm + i * 16 + quad * 4;
#pragma unroll
      for (int j = 0; j < NI; ++j) {
        int n = (int)tn0 + wn + j * 16 + l16;
        float bvs = bias[n];
#pragma unroll
        for (int r = 0; r < 4; ++r) {
          float v = acc[i][j][r] + bvs;
          v = fmaxf(v, 0.0f);
          C[(size_t)(m0 + r) * N + n] = f2bf(v);
        }
      }
    }
  } else {  // EPI == 3: bf16 partial, slab per grid.y
    unsigned short* C = (unsigned short*)C0out + (size_t)blockIdx.y * NUMM * BM * N;
#pragma unroll
    for (int i = 0; i < MI; ++i) {
      long m0 = tm0 + wm + i * 16 + quad * 4;
#pragma unroll
      for (int j = 0; j < NI; ++j) {
        int n = (int)tn0 + wn + j * 16 + l16;
#pragma unroll
        for (int r = 0; r < 4; ++r) C[(size_t)(m0 + r) * N + n] = f2bf(acc[i][j][r]);
      }
    }
  }
}

// ---------------- layer-2 gather + bias + p_r + log_softmax (fused, reads split-K P) ----
__global__ __launch_bounds__(128) void gather2_final_kernel(const unsigned short* __restrict__ P,
                                                            const int* __restrict__ offs,
                                                            const int* __restrict__ csr,
                                                            const float* __restrict__ b2,
                                                            float* __restrict__ out) {
  int i = blockIdx.x;
  int t = threadIdx.x;  // 0..127
  const unsigned short* P1 = P + (size_t)M_PAD * 512;
  int beg = offs[i], end = offs[i + 1];
  float a0 = 0.f, a1 = 0.f, c0 = 0.f, c1 = 0.f;
  int j = beg;
  for (; j + 2 <= end; j += 2) {
    int s0 = __builtin_amdgcn_readfirstlane(csr[j]);
    int s1 = __builtin_amdgcn_readfirstlane(csr[j + 1]);
    unsigned int u0 = ((const unsigned int*)(P + (size_t)s0 * 512))[t];
    unsigned int w0 = ((const unsigned int*)(P1 + (size_t)s0 * 512))[t];
    unsigned int u1 = ((const unsigned int*)(P + (size_t)s1 * 512))[t];
    unsigned int w1 = ((const unsigned int*)(P1 + (size_t)s1 * 512))[t];
    a0 += bf2f((unsigned short)(u0 & 0xffffu)) + bf2f((unsigned short)(w0 & 0xffffu));
    a1 += bf2f((unsigned short)(u0 >> 16)) + bf2f((unsigned short)(w0 >> 16));
    c0 += bf2f((unsigned short)(u1 & 0xffffu)) + bf2f((unsigned short)(w1 & 0xffffu));
    c1 += bf2f((unsigned short)(u1 >> 16)) + bf2f((unsigned short)(w1 >> 16));
  }
  if (j < end) {
    int s0 = __builtin_amdgcn_readfirstlane(csr[j]);
    unsigned int u0 = ((const unsigned int*)(P + (size_t)s0 * 512))[t];
    unsigned int w0 = ((const unsigned int*)(P1 + (size_t)s0 * 512))[t];
    a0 += bf2f((unsigned short)(u0 & 0xffffu)) + bf2f((unsigned short)(w0 & 0xffffu));
    a1 += bf2f((unsigned short)(u0 >> 16)) + bf2f((unsigned short)(w0 >> 16));
  }
  float inv = 1.0f / (float)max(end - beg, 1);
  float2 bv = ((const float2*)b2)[t];
  // self p_r term: cols 256+2t, 257+2t of both partial slabs
  unsigned int su = ((const unsigned int*)(P + (size_t)i * 512))[128 + t];
  unsigned int sw = ((const unsigned int*)(P1 + (size_t)i * 512))[128 + t];
  float pv0 = bf2f((unsigned short)(su & 0xffffu)) + bf2f((unsigned short)(sw & 0xffffu));
  float pv1 = bf2f((unsigned short)(su >> 16)) + bf2f((unsigned short)(sw >> 16));
  float v0 = (a0 + c0) * inv + bv.x + pv0;
  float v1 = (a1 + c1) * inv + bv.y + pv1;

  __shared__ float sm[2], ss[2];
  int w = t >> 6;
  float m = fmaxf(v0, v1);
#pragma unroll
  for (int o = 32; o > 0; o >>= 1) m = fmaxf(m, __shfl_xor(m, o, 64));
  if ((t & 63) == 0) sm[w] = m;
  __syncthreads();
  m = fmaxf(sm[0], sm[1]);

  float s = __expf(v0 - m) + __expf(v1 - m);
#pragma unroll
  for (int o = 32; o > 0; o >>= 1) s += __shfl_xor(s, o, 64);
  if ((t & 63) == 0) ss[w] = s;
  __syncthreads();
  float ls = logf(ss[0] + ss[1]);

  float2 o2 = {v0 - m - ls, v1 - m - ls};
  ((float2*)(out + (size_t)i * OUTD))[t] = o2;
}

// ---------------- workspace layout (bytes) ----------------
static constexpr size_t OFF_A1 = 0;
static constexpr size_t OFF_XBF = OFF_A1 + (size_t)M_PAD * 1024 * 2;
static constexpr size_t OFF_W1 = OFF_XBF + (size_t)M_PAD * 1024 * 2;
static constexpr size_t OFF_HB = OFF_W1 + (size_t)HID * 2048 * 2;
static constexpr size_t OFF_W2 = OFF_HB + (size_t)M_PAD * HID * 2;
static constexpr size_t OFF_DEG = OFF_W2 + (size_t)512 * HID * 2;
static constexpr size_t OFF_OFFS = OFF_DEG + (size_t)NN * 4;
static constexpr size_t OFF_CUR = OFF_OFFS + (size_t)(NN + 4) * 4;
static constexpr size_t OFF_CSR = OFF_CUR + (size_t)NN * 4;
static constexpr size_t OFF_P = OFF_A1;  // [2][M_PAD][512] bf16 = 20.7 MB, fits A1 region

extern "C" void kernel_launch(void* const* d_in, const int* in_sizes, int n_in,
                              void* d_out, int out_size, void* d_ws, size_t ws_size,
                              hipStream_t stream) {
  const float* x = (const float*)d_in[0];
  const int* ei = (const int*)d_in[1];
  const int* src = ei;
  const int* dst = ei + NE;
  const float* W1_l = (const float*)d_in[2];
  const float* b1_l = (const float*)d_in[3];
  const float* W1_r = (const float*)d_in[4];
  const float* W2_l = (const float*)d_in[5];
  const float* b2_l = (const float*)d_in[6];
  const float* W2_r = (const float*)d_in[7];
  float* out = (float*)d_out;

  char* ws = (char*)d_ws;
  unsigned short* A1 = (unsigned short*)(ws + OFF_A1);
  unsigned short* x_bf = (unsigned short*)(ws + OFF_XBF);
  unsigned short* w1cat = (unsigned short*)(ws + OFF_W1);
  unsigned short* h_b = (unsigned short*)(ws + OFF_HB);
  unsigned short* w2cat = (unsigned short*)(ws + OFF_W2);
  int* deg = (int*)(ws + OFF_DEG);
  int* offs = (int*)(ws + OFF_OFFS);
  int* cur = (int*)(ws + OFF_CUR);
  int* csr = (int*)(ws + OFF_CSR);
  unsigned short* P = (unsigned short*)(ws + OFF_P);

  // zero degree counters (ws is poisoned 0xAA before every call)
  hipMemsetAsync(deg, 0, (size_t)NN * 4, stream);

  // fused prep: weight converts + x->bf16 + degree count
  prep_kernel<<<PREP_NB, 256, 0, stream>>>(W1_l, W1_r, W2_l, W2_r, x, dst,
                                           w1cat, w2cat, x_bf, deg);
  scan_kernel<<<1, 1024, 0, stream>>>(deg, offs, cur);
  bin_kernel<<<(NE + 255) / 256, 256, 0, stream>>>(src, dst, cur, csr);

  // A1 = mean agg (bf16) via CSR gather; pad rows of A1 AND x_bf zeroed here
  gather1_kernel<<<M_PAD, 256, 0, stream>>>(x_bf, offs, csr, A1);

  // h = relu([A1 | x_bf] @ w1cat^T + b1) -> bf16 [10112][4096]
  // 256^2 tile, 8 waves, counted-vmcnt phased schedule; grid = 40 m-tiles x 16 n-tiles
  gemm1_8ph_kernel<<<40 * 16, 512, 0, stream>>>(A1, x_bf, w1cat, b1_l, h_b);

  // split-K=2, BN=256: P[s] = h[:, s*2048:(s+1)*2048] @ w2cat[:, same]^T -> bf16 [2][M][512]
  gemm_kernel<64, 256, 64, 4096, 2, 512, 158, 2, 1, 3, 4, false>
      <<<dim3(158 * 2, 2), 256, 0, stream>>>(h_b, nullptr, w2cat, nullptr, P);

  // mean of p_l over in-edges + bias + p_r (both summed from split-K partials), log_softmax
  gather2_final_kernel<<<NN, 128, 0, stream>>>(P, offs, csr, b2_l, out);
}

// Round 4
// 461.315 us; speedup vs baseline: 1.0352x; 1.0352x over previous
//
#include <hip/hip_runtime.h>
#include <cstdint>
#include <cstddef>

#define DEVINL __device__ __forceinline__

typedef __bf16 bf16x8 __attribute__((ext_vector_type(8)));
typedef float f32x4 __attribute__((ext_vector_type(4)));

static constexpr int NN = 10000;     // nodes
static constexpr int NE = 80000;     // edges
static constexpr int IN_DIM = 1024;
static constexpr int HID = 4096;
static constexpr int OUTD = 256;
static constexpr int M_PAD = 10112;  // 79*128 (also 158*64)

// fp32 -> bf16 round-nearest-even
DEVINL unsigned short f2bf(float f) {
  unsigned int u = __builtin_bit_cast(unsigned int, f);
  u += 0x7fffu + ((u >> 16) & 1u);
  return (unsigned short)(u >> 16);
}
DEVINL float bf2f(unsigned short h) {
  unsigned int u = ((unsigned int)h) << 16;
  return __builtin_bit_cast(float, u);
}

// async global->LDS, 16B per lane; LDS dest is wave-uniform base + lane*16
DEVINL void ld_lds16(const void* g, void* l) {
  __builtin_amdgcn_global_load_lds(
      (const __attribute__((address_space(1))) unsigned int*)g,
      (__attribute__((address_space(3))) unsigned int*)l, 16, 0, 0);
}

// ---------------- fused prep: conv_w1 + conv_w2 + x->bf16 + degree count ----------------
static constexpr int PREP_B1 = 8192;
static constexpr int PREP_B2 = PREP_B1 + 2048;
static constexpr int PREP_B3 = PREP_B2 + 10000;
static constexpr int PREP_NB = PREP_B3 + 313;

__global__ __launch_bounds__(256) void prep_kernel(
    const float* __restrict__ W1l, const float* __restrict__ W1r,
    const float* __restrict__ W2l, const float* __restrict__ W2r,
    const float* __restrict__ x, const int* __restrict__ dst,
    unsigned short* __restrict__ w1cat, unsigned short* __restrict__ w2cat,
    unsigned short* __restrict__ x_bf, int* __restrict__ deg) {
  int b = blockIdx.x;
  int t = threadIdx.x;
  if (b < PREP_B1) {  // w1cat [4096][2048]: row n = [W1_l row n | W1_r row n]
    int g = b * 256 + t;
    int n = g >> 9;
    int kg = g & 511;
    const float* s = (kg < 256) ? (W1l + (size_t)n * 1024 + kg * 4)
                                : (W1r + (size_t)n * 1024 + (kg - 256) * 4);
    float4 v = *(const float4*)s;
    ushort4 p = {f2bf(v.x), f2bf(v.y), f2bf(v.z), f2bf(v.w)};
    ((ushort4*)w1cat)[g] = p;
  } else if (b < PREP_B2) {  // w2cat [512][4096]: rows 0..255 = W2_l, 256..511 = W2_r
    int g = (b - PREP_B1) * 256 + t;
    int n = g >> 10;
    int kg = g & 1023;
    const float* s = (n < 256) ? (W2l + (size_t)n * 4096 + kg * 4)
                               : (W2r + (size_t)(n - 256) * 4096 + kg * 4);
    float4 v = *(const float4*)s;
    ushort4 p = {f2bf(v.x), f2bf(v.y), f2bf(v.z), f2bf(v.w)};
    ((ushort4*)w2cat)[g] = p;
  } else if (b < PREP_B3) {  // x -> bf16, [10000][1024]
    int g = (b - PREP_B2) * 256 + t;
    int i = g >> 8;
    int kg = g & 255;
    float4 v = ((const float4*)(x + (size_t)i * IN_DIM))[kg];
    ushort4 p = {f2bf(v.x), f2bf(v.y), f2bf(v.z), f2bf(v.w)};
    ((ushort4*)(x_bf + (size_t)i * IN_DIM))[kg] = p;
  } else {  // degree count
    int e = (b - PREP_B3) * 256 + t;
    if (e < NE) atomicAdd(&deg[dst[e]], 1);
  }
}

// one-block exclusive scan over NN degrees -> offs[0..NN] and cursor copy cur[]
__global__ __launch_bounds__(1024) void scan_kernel(const int* __restrict__ deg,
                                                    int* __restrict__ offs,
                                                    int* __restrict__ cur) {
  __shared__ int part[1024];
  constexpr int NPT = 10;  // 1024*10 = 10240 >= NN
  int t = threadIdx.x;
  int base = t * NPT;
  int s = 0;
  for (int j = 0; j < NPT; ++j) {
    int n = base + j;
    s += (n < NN) ? deg[n] : 0;
  }
  part[t] = s;
  __syncthreads();
  for (int o = 1; o < 1024; o <<= 1) {  // Hillis-Steele inclusive scan
    int v = (t >= o) ? part[t - o] : 0;
    __syncthreads();
    part[t] += v;
    __syncthreads();
  }
  int pre = (t > 0) ? part[t - 1] : 0;
  for (int j = 0; j < NPT; ++j) {
    int n = base + j;
    if (n < NN) {
      offs[n] = pre;
      cur[n] = pre;
      pre += deg[n];
    }
  }
  if (t == 1023) offs[NN] = part[1023];  // == NE
}

// bin edges: csr[cur[dst]++] = src  (cur pre-seeded with offs by scan)
__global__ void bin_kernel(const int* __restrict__ src, const int* __restrict__ dst,
                           int* __restrict__ cur, int* __restrict__ csr) {
  int e = blockIdx.x * 256 + threadIdx.x;
  if (e < NE) {
    int p = atomicAdd(&cur[dst[e]], 1);
    csr[p] = src[e];
  }
}

// ---------------- layer-1 gather (bf16 source): A1 = mean_agg(x) only ----------------
__global__ __launch_bounds__(256) void gather1_kernel(unsigned short* __restrict__ x_bf,
                                                      const int* __restrict__ offs,
                                                      const int* __restrict__ csr,
                                                      unsigned short* __restrict__ A1) {
  int i = blockIdx.x;
  int t = threadIdx.x;  // 256 threads x ushort4 = 1024 bf16 = one row
  unsigned short* row = A1 + (size_t)i * 1024;
  if (i >= NN) {
    ushort4 z = {0, 0, 0, 0};
    ((ushort4*)row)[t] = z;
    ((ushort4*)(x_bf + (size_t)i * 1024))[t] = z;
    return;
  }
  int beg = offs[i], end = offs[i + 1];
  float4 a0 = {0.f, 0.f, 0.f, 0.f}, a1 = {0.f, 0.f, 0.f, 0.f};
  int j = beg;
  for (; j + 2 <= end; j += 2) {
    int s0 = __builtin_amdgcn_readfirstlane(csr[j]);
    int s1 = __builtin_amdgcn_readfirstlane(csr[j + 1]);
    ushort4 u0 = ((const ushort4*)(x_bf + (size_t)s0 * IN_DIM))[t];
    ushort4 u1 = ((const ushort4*)(x_bf + (size_t)s1 * IN_DIM))[t];
    a0.x += bf2f(u0.x); a0.y += bf2f(u0.y); a0.z += bf2f(u0.z); a0.w += bf2f(u0.w);
    a1.x += bf2f(u1.x); a1.y += bf2f(u1.y); a1.z += bf2f(u1.z); a1.w += bf2f(u1.w);
  }
  if (j < end) {
    int s0 = __builtin_amdgcn_readfirstlane(csr[j]);
    ushort4 u0 = ((const ushort4*)(x_bf + (size_t)s0 * IN_DIM))[t];
    a0.x += bf2f(u0.x); a0.y += bf2f(u0.y); a0.z += bf2f(u0.z); a0.w += bf2f(u0.w);
  }
  float inv = 1.0f / (float)max(end - beg, 1);
  ushort4 pa = {f2bf((a0.x + a1.x) * inv), f2bf((a0.y + a1.y) * inv),
                f2bf((a0.z + a1.z) * inv), f2bf((a0.w + a1.w) * inv)};
  ((ushort4*)row)[t] = pa;
}

// ---------------- GEMM1: 256x256 tile, 8 waves, faithful m201-style 4-phase/K-tile ------
// R3 post-mortem fix vs the R2 coarse split (which regressed to 254 µs / 28.5% MfmaUtil):
//  * per-phase fine interleave: phase q reads ONLY quadrant q's A-frags (+ all B at q=0,
//    12 ds_reads -> lgkmcnt(8) throttle), stage issue spread (A of t+1 at q=0, B at q=1),
//    exactly 2 barriers/phase (8/K-tile, was 9).
//  * loads stay in flight across 8 barriers: tile-boundary s_waitcnt vmcnt(0) placed AFTER
//    phase 3's MFMA — by then t+1's stages are 3-4 phases (~2000 cyc) old, so the wait is
//    ~free; nothing just-issued is ever drained (T4 mechanism, m218).
//  * rule #18: sched_barrier(0) after each asm lgkmcnt(0) so MFMA can't hoist past it.
// Hazards: reads of buf[t] follow prev tile's vmcnt(0)+barrier (stage-complete, all waves);
// stage writes to buf[t^1] follow tile t-1's closing barrier (its reads all consumed).
// LDS chunk swizzle unchanged (0 conflicts measured). M-tail: clamp src rows, guard stores.
__global__ __launch_bounds__(512) void gemm1_8ph_kernel(
    const unsigned short* __restrict__ A,    // A1  (k < 1024), row stride 1024
    const unsigned short* __restrict__ A2,   // x_bf (k >= 1024), row stride 1024
    const unsigned short* __restrict__ Bt,   // w1cat [4096][2048]
    const float* __restrict__ bias,
    unsigned short* __restrict__ C) {
  constexpr int BM = 256, BN = 256, BK = 64;
  constexpr int K = 2048, N = 4096;
  constexpr int NT = K / BK;  // 32
  constexpr int NUMN = 16, GM = 8, NPG = GM * NUMN;

  __shared__ unsigned short Asm[2][BM * BK];  // 2 x 32 KiB
  __shared__ unsigned short Bsm[2][BN * BK];  // 2 x 32 KiB (total 128 KiB)

  // grouped swizzle (m-fastest within GM band): B n-panel reused across 8 blocks
  const int pid = blockIdx.x;
  const int gid = pid / NPG;
  const int first_m = gid * GM;  // 40 = 5*8, bands exact
  const int local = pid % NPG;
  const int pm = first_m + (local % GM);
  const int pn = local / GM;
  const long tm0 = (long)pm * BM;
  const long tn0 = (long)pn * BN;

  const int tid = threadIdx.x;  // 0..511
  const int lane = tid & 63;
  const int wave = tid >> 6;    // 0..7
  const int quad = lane >> 4;
  const int l16 = lane & 15;
  const int l7 = l16 & 7;
  const int wm = (wave >> 2) * 128;  // A-half: rows wm..wm+127
  const int wn = (wave & 3) * 64;    // B quarter

  f32x4 acc[8][4];
#pragma unroll
  for (int i = 0; i < 8; ++i)
#pragma unroll
    for (int j = 0; j < 4; ++j) acc[i][j] = (f32x4){0.f, 0.f, 0.f, 0.f};

  // staging map: chunk c = s*512 + tid; tile row r = c>>3; physical slot = c&7;
  // source logical chunk g = slot ^ (r&7); LDS dest linear (wave-uniform + lane*16)
  size_t aOffE[4], bOffE[4];
#pragma unroll
  for (int s = 0; s < 4; ++s) {
    int c = s * 512 + tid;
    int r = c >> 3;
    int g = (c & 7) ^ (r & 7);
    long ra = tm0 + r;
    if (ra > M_PAD - 1) ra = M_PAD - 1;  // clamp into zeroed pad row
    aOffE[s] = (size_t)ra * 1024 + g * 8;
    bOffE[s] = (size_t)(tn0 + r) * K + g * 8;
  }

#define STAGE_A(kt, buf)                                                          \
  {                                                                               \
    const unsigned short* ab_ = ((kt) < NT / 2) ? A : A2;                         \
    const int ka_ = ((kt) & (NT / 2 - 1)) * BK;                                   \
    _Pragma("unroll") for (int s_ = 0; s_ < 4; ++s_)                              \
        ld_lds16(ab_ + aOffE[s_] + ka_, &Asm[(buf)][(s_ * 512 + wave * 64) * 8]); \
  }
#define STAGE_B(kt, buf)                                                          \
  {                                                                               \
    const int k0_ = (kt)*BK;                                                      \
    _Pragma("unroll") for (int s_ = 0; s_ < 4; ++s_)                              \
        ld_lds16(Bt + bOffE[s_] + k0_, &Bsm[(buf)][(s_ * 512 + wave * 64) * 8]); \
  }

  // prologue: tile 0 fully staged, drained once (outside main loop)
  STAGE_A(0, 0)
  STAGE_B(0, 0)
  asm volatile("s_waitcnt vmcnt(0)" ::: "memory");
  __builtin_amdgcn_s_barrier();

  for (int kt = 0; kt < NT; ++kt) {
    const int buf = kt & 1;
    const unsigned short* As = Asm[buf];
    const unsigned short* Bs = Bsm[buf];

    // ---------- phase 0: 8 B-frags + 4 A-frags (q0) | stage A(t+1) | MFMA q0 ----------
    bf16x8 bv[2][4];
#pragma unroll
    for (int kk = 0; kk < 2; ++kk)
#pragma unroll
      for (int nj = 0; nj < 4; ++nj)
        bv[kk][nj] =
            *(const bf16x8*)(Bs + (wn + nj * 16 + l16) * BK + (((kk * 4 + quad) ^ l7) * 8));
    {
      bf16x8 af[2][2];
#pragma unroll
      for (int kk = 0; kk < 2; ++kk)
#pragma unroll
        for (int i = 0; i < 2; ++i)
          af[kk][i] =
              *(const bf16x8*)(As + (wm + i * 16 + l16) * BK + (((kk * 4 + quad) ^ l7) * 8));
      if (kt + 1 < NT) STAGE_A(kt + 1, buf ^ 1)
      asm volatile("s_waitcnt lgkmcnt(8)" ::: "memory");  // throttle: 12 reads issued
      __builtin_amdgcn_s_barrier();
      asm volatile("s_waitcnt lgkmcnt(0)" ::: "memory");
      __builtin_amdgcn_sched_barrier(0);
      __builtin_amdgcn_s_setprio(1);
#pragma unroll
      for (int kk = 0; kk < 2; ++kk)
#pragma unroll
        for (int i = 0; i < 2; ++i)
#pragma unroll
          for (int nj = 0; nj < 4; ++nj)
            acc[i][nj] = __builtin_amdgcn_mfma_f32_16x16x32_bf16(af[kk][i], bv[kk][nj],
                                                                 acc[i][nj], 0, 0, 0);
      __builtin_amdgcn_s_setprio(0);
      __builtin_amdgcn_s_barrier();
      __builtin_amdgcn_sched_barrier(0);
    }

    // ---------- phases 1..3: 4 A-frags (quadrant q) | stage B(t+1) at q=1 | MFMA q ----
#pragma unroll
    for (int q = 1; q < 4; ++q) {
      bf16x8 af[2][2];
#pragma unroll
      for (int kk = 0; kk < 2; ++kk)
#pragma unroll
        for (int i = 0; i < 2; ++i)
          af[kk][i] = *(const bf16x8*)(As + (wm + (q * 2 + i) * 16 + l16) * BK +
                                       (((kk * 4 + quad) ^ l7) * 8));
      if (q == 1 && kt + 1 < NT) STAGE_B(kt + 1, buf ^ 1)
      __builtin_amdgcn_s_barrier();
      asm volatile("s_waitcnt lgkmcnt(0)" ::: "memory");
      __builtin_amdgcn_sched_barrier(0);
      __builtin_amdgcn_s_setprio(1);
#pragma unroll
      for (int kk = 0; kk < 2; ++kk)
#pragma unroll
        for (int i = 0; i < 2; ++i)
#pragma unroll
          for (int nj = 0; nj < 4; ++nj)
            acc[q * 2 + i][nj] = __builtin_amdgcn_mfma_f32_16x16x32_bf16(
                af[kk][i], bv[kk][nj], acc[q * 2 + i][nj], 0, 0, 0);
      __builtin_amdgcn_s_setprio(0);
      if (q == 3) {
        // tile-boundary wait: t+1's stages were issued 3-4 phases ago -> ~free,
        // and nothing just-issued is drained (loads spanned 8 barriers in flight)
        asm volatile("s_waitcnt vmcnt(0)" ::: "memory");
      }
      __builtin_amdgcn_s_barrier();
      __builtin_amdgcn_sched_barrier(0);
    }
  }
#undef STAGE_A
#undef STAGE_B

  // epilogue: relu(acc + bias) -> bf16; C/D layout col = lane&15, row = quad*4 + reg
#pragma unroll
  for (int mi = 0; mi < 8; ++mi) {
    long m0 = tm0 + wm + mi * 16 + quad * 4;
#pragma unroll
    for (int nj = 0; nj < 4; ++nj) {
      int n = (int)tn0 + wn + nj * 16 + l16;
      float bvs = bias[n];
#pragma unroll
      for (int r = 0; r < 4; ++r) {
        long m = m0 + r;
        if (m < M_PAD) {
          float v = fmaxf(acc[mi][nj][r] + bvs, 0.0f);
          C[(size_t)m * N + n] = f2bf(v);
        }
      }
    }
  }
}

// ---------------- bf16 MFMA GEMM, templated (kept for GEMM2) ----------------
template <int BM, int BN, int BK, int K, int KSPLIT, int N, int NUMM, int NUMN, int GM,
          int EPI, int NWY, bool ASPLIT>
__global__ __launch_bounds__(256) void gemm_kernel(const unsigned short* __restrict__ A,
                                                   const unsigned short* __restrict__ A2,
                                                   const unsigned short* __restrict__ Bt,
                                                   const float* __restrict__ bias,
                                                   void* __restrict__ C0out) {
  constexpr int MGR = 4 / NWY;            // waves along m
  constexpr int MI = BM / 16 / MGR;       // 16-row tiles per wave
  constexpr int NI = 4;                   // 16-col tiles per wave (BN = NWY*64)
  constexpr int CPR = BK / 8;             // 16B chunks per LDS row
  constexpr int SA = BM * CPR / 256;      // staging rounds for A (256 thr x 16B)
  constexpr int SB = BN * CPR / 256;
  constexpr int KK = BK / 32;             // MFMA k-steps per tile
  constexpr int KS = K / KSPLIT;          // K range per split
  constexpr int AS = ASPLIT ? K / 2 : K;  // A row stride
  __shared__ unsigned short Asm[BM * BK];
  __shared__ unsigned short Bsm[BN * BK];

  constexpr int NPG = GM * NUMN;
  const int pid = blockIdx.x;
  const int gid = pid / NPG;
  const int first_m = gid * GM;
  const int sz = (NUMM - first_m < GM) ? (NUMM - first_m) : GM;
  const int local = pid % NPG;
  const int pm = first_m + local % sz;
  const int pn = local / sz;
  const int koff = (KSPLIT > 1) ? (int)blockIdx.y * KS : 0;

  const int tid = threadIdx.x;
  const int lane = tid & 63;
  const int wave = tid >> 6;
  const int quad = lane >> 4;
  const int l16 = lane & 15;
  const int wm = (wave % MGR) * (BM / MGR);
  const int wn = (wave / MGR) * 64;
  const long tm0 = (long)pm * BM;
  const long tn0 = (long)pn * BN;

  f32x4 acc[MI][NI];
#pragma unroll
  for (int i = 0; i < MI; ++i)
#pragma unroll
    for (int j = 0; j < NI; ++j) acc[i][j] = (f32x4){0.f, 0.f, 0.f, 0.f};

  size_t aOff[SA];
  unsigned short* aDst[SA];
  const unsigned short* bSrc[SB];
  unsigned short* bDst[SB];
#pragma unroll
  for (int s = 0; s < SA; ++s) {
    int c = s * 256 + wave * 64 + lane;
    int r = c / CPR;
    int g = (c % CPR) ^ (r & 7);
    aOff[s] = (size_t)(tm0 + r) * AS + koff + g * 8;
    aDst[s] = Asm + s * 2048 + wave * 512;  // wave-uniform base
  }
#pragma unroll
  for (int s = 0; s < SB; ++s) {
    int c = s * 256 + wave * 64 + lane;
    int r = c / CPR;
    int g = (c % CPR) ^ (r & 7);
    bSrc[s] = Bt + (size_t)(tn0 + r) * K + koff + g * 8;
    bDst[s] = Bsm + s * 2048 + wave * 512;
  }

  const int l7 = l16 & 7;

  for (int k0 = 0; k0 < KS; k0 += BK) {
    const unsigned short* ab = (!ASPLIT || k0 < K / 2) ? A : A2;
    const int ka = ASPLIT ? (k0 & (K / 2 - 1)) : k0;
#pragma unroll
    for (int s = 0; s < SA; ++s) ld_lds16(ab + aOff[s] + ka, aDst[s]);
#pragma unroll
    for (int s = 0; s < SB; ++s) ld_lds16(bSrc[s] + k0, bDst[s]);
    __syncthreads();  // drains vmcnt -> LDS tiles complete

#pragma unroll
    for (int kk = 0; kk < KK; ++kk) {
      const int p = (kk * 4 + quad) ^ l7;  // physical chunk for this frag
      bf16x8 af[MI], bv[NI];
#pragma unroll
      for (int i = 0; i < MI; ++i) {
        int ra = wm + i * 16 + l16;
        af[i] = *(const bf16x8*)(Asm + ra * BK + p * 8);
      }
#pragma unroll
      for (int j = 0; j < NI; ++j) {
        int rb = wn + j * 16 + l16;
        bv[j] = *(const bf16x8*)(Bsm + rb * BK + p * 8);
      }
#pragma unroll
      for (int i = 0; i < MI; ++i)
#pragma unroll
        for (int j = 0; j < NI; ++j)
          acc[i][j] = __builtin_amdgcn_mfma_f32_16x16x32_bf16(af[i], bv[j], acc[i][j], 0, 0, 0);
    }
    __syncthreads();  // LDS reads done before next stage overwrites
  }

  if (EPI == 1) {
    unsigned short* C = (unsigned short*)C0out;
#pragma unroll
    for (int i = 0; i < MI; ++i) {
      long m0 = tm0 + wm + i * 16 + quad * 4;
#pragma unroll
      for (int j = 0; j < NI; ++j) {
        int n = (int)tn0 + wn + j * 16 + l16;
        float bvs = bias[n];
#pragma unroll
        for (int r = 0; r < 4; ++r) {
          float v = acc[i][j][r] + bvs;
          v = fmaxf(v, 0.0f);
          C[(size_t)(m0 + r) * N + n] = f2bf(v);
        }
      }
    }
  } else {  // EPI == 3: bf16 partial, slab per grid.y
    unsigned short* C = (unsigned short*)C0out + (size_t)blockIdx.y * NUMM * BM * N;
#pragma unroll
    for (int i = 0; i < MI; ++i) {
      long m0 = tm0 + wm + i * 16 + quad * 4;
#pragma unroll
      for (int j = 0; j < NI; ++j) {
        int n = (int)tn0 + wn + j * 16 + l16;
#pragma unroll
        for (int r = 0; r < 4; ++r) C[(size_t)(m0 + r) * N + n] = f2bf(acc[i][j][r]);
      }
    }
  }
}

// ---------------- layer-2 gather + bias + p_r + log_softmax (fused, reads split-K P) ----
__global__ __launch_bounds__(128) void gather2_final_kernel(const unsigned short* __restrict__ P,
                                                            const int* __restrict__ offs,
                                                            const int* __restrict__ csr,
                                                            const float* __restrict__ b2,
                                                            float* __restrict__ out) {
  int i = blockIdx.x;
  int t = threadIdx.x;  // 0..127
  const unsigned short* P1 = P + (size_t)M_PAD * 512;
  int beg = offs[i], end = offs[i + 1];
  float a0 = 0.f, a1 = 0.f, c0 = 0.f, c1 = 0.f;
  int j = beg;
  for (; j + 2 <= end; j += 2) {
    int s0 = __builtin_amdgcn_readfirstlane(csr[j]);
    int s1 = __builtin_amdgcn_readfirstlane(csr[j + 1]);
    unsigned int u0 = ((const unsigned int*)(P + (size_t)s0 * 512))[t];
    unsigned int w0 = ((const unsigned int*)(P1 + (size_t)s0 * 512))[t];
    unsigned int u1 = ((const unsigned int*)(P + (size_t)s1 * 512))[t];
    unsigned int w1 = ((const unsigned int*)(P1 + (size_t)s1 * 512))[t];
    a0 += bf2f((unsigned short)(u0 & 0xffffu)) + bf2f((unsigned short)(w0 & 0xffffu));
    a1 += bf2f((unsigned short)(u0 >> 16)) + bf2f((unsigned short)(w0 >> 16));
    c0 += bf2f((unsigned short)(u1 & 0xffffu)) + bf2f((unsigned short)(w1 & 0xffffu));
    c1 += bf2f((unsigned short)(u1 >> 16)) + bf2f((unsigned short)(w1 >> 16));
  }
  if (j < end) {
    int s0 = __builtin_amdgcn_readfirstlane(csr[j]);
    unsigned int u0 = ((const unsigned int*)(P + (size_t)s0 * 512))[t];
    unsigned int w0 = ((const unsigned int*)(P1 + (size_t)s0 * 512))[t];
    a0 += bf2f((unsigned short)(u0 & 0xffffu)) + bf2f((unsigned short)(w0 & 0xffffu));
    a1 += bf2f((unsigned short)(u0 >> 16)) + bf2f((unsigned short)(w0 >> 16));
  }
  float inv = 1.0f / (float)max(end - beg, 1);
  float2 bv = ((const float2*)b2)[t];
  unsigned int su = ((const unsigned int*)(P + (size_t)i * 512))[128 + t];
  unsigned int sw = ((const unsigned int*)(P1 + (size_t)i * 512))[128 + t];
  float pv0 = bf2f((unsigned short)(su & 0xffffu)) + bf2f((unsigned short)(sw & 0xffffu));
  float pv1 = bf2f((unsigned short)(su >> 16)) + bf2f((unsigned short)(sw >> 16));
  float v0 = (a0 + c0) * inv + bv.x + pv0;
  float v1 = (a1 + c1) * inv + bv.y + pv1;

  __shared__ float sm[2], ss[2];
  int w = t >> 6;
  float m = fmaxf(v0, v1);
#pragma unroll
  for (int o = 32; o > 0; o >>= 1) m = fmaxf(m, __shfl_xor(m, o, 64));
  if ((t & 63) == 0) sm[w] = m;
  __syncthreads();
  m = fmaxf(sm[0], sm[1]);

  float s = __expf(v0 - m) + __expf(v1 - m);
#pragma unroll
  for (int o = 32; o > 0; o >>= 1) s += __shfl_xor(s, o, 64);
  if ((t & 63) == 0) ss[w] = s;
  __syncthreads();
  float ls = logf(ss[0] + ss[1]);

  float2 o2 = {v0 - m - ls, v1 - m - ls};
  ((float2*)(out + (size_t)i * OUTD))[t] = o2;
}

// ---------------- workspace layout (bytes) ----------------
static constexpr size_t OFF_A1 = 0;
static constexpr size_t OFF_XBF = OFF_A1 + (size_t)M_PAD * 1024 * 2;
static constexpr size_t OFF_W1 = OFF_XBF + (size_t)M_PAD * 1024 * 2;
static constexpr size_t OFF_HB = OFF_W1 + (size_t)HID * 2048 * 2;
static constexpr size_t OFF_W2 = OFF_HB + (size_t)M_PAD * HID * 2;
static constexpr size_t OFF_DEG = OFF_W2 + (size_t)512 * HID * 2;
static constexpr size_t OFF_OFFS = OFF_DEG + (size_t)NN * 4;
static constexpr size_t OFF_CUR = OFF_OFFS + (size_t)(NN + 4) * 4;
static constexpr size_t OFF_CSR = OFF_CUR + (size_t)NN * 4;
static constexpr size_t OFF_P = OFF_A1;  // [2][M_PAD][512] bf16 = 20.7 MB, fits A1 region

extern "C" void kernel_launch(void* const* d_in, const int* in_sizes, int n_in,
                              void* d_out, int out_size, void* d_ws, size_t ws_size,
                              hipStream_t stream) {
  const float* x = (const float*)d_in[0];
  const int* ei = (const int*)d_in[1];
  const int* src = ei;
  const int* dst = ei + NE;
  const float* W1_l = (const float*)d_in[2];
  const float* b1_l = (const float*)d_in[3];
  const float* W1_r = (const float*)d_in[4];
  const float* W2_l = (const float*)d_in[5];
  const float* b2_l = (const float*)d_in[6];
  const float* W2_r = (const float*)d_in[7];
  float* out = (float*)d_out;

  char* ws = (char*)d_ws;
  unsigned short* A1 = (unsigned short*)(ws + OFF_A1);
  unsigned short* x_bf = (unsigned short*)(ws + OFF_XBF);
  unsigned short* w1cat = (unsigned short*)(ws + OFF_W1);
  unsigned short* h_b = (unsigned short*)(ws + OFF_HB);
  unsigned short* w2cat = (unsigned short*)(ws + OFF_W2);
  int* deg = (int*)(ws + OFF_DEG);
  int* offs = (int*)(ws + OFF_OFFS);
  int* cur = (int*)(ws + OFF_CUR);
  int* csr = (int*)(ws + OFF_CSR);
  unsigned short* P = (unsigned short*)(ws + OFF_P);

  // zero degree counters (ws is poisoned 0xAA before every call)
  hipMemsetAsync(deg, 0, (size_t)NN * 4, stream);

  prep_kernel<<<PREP_NB, 256, 0, stream>>>(W1_l, W1_r, W2_l, W2_r, x, dst,
                                           w1cat, w2cat, x_bf, deg);
  scan_kernel<<<1, 1024, 0, stream>>>(deg, offs, cur);
  bin_kernel<<<(NE + 255) / 256, 256, 0, stream>>>(src, dst, cur, csr);

  gather1_kernel<<<M_PAD, 256, 0, stream>>>(x_bf, offs, csr, A1);

  // h = relu([A1 | x_bf] @ w1cat^T + b1) -> bf16 [10112][4096]
  // 256^2 tile, 8 waves, 4-phase/K-tile counted-wait schedule; grid = 40 x 16
  gemm1_8ph_kernel<<<40 * 16, 512, 0, stream>>>(A1, x_bf, w1cat, b1_l, h_b);

  // split-K=2, BN=256: P[s] = h[:, s*2048:(s+1)*2048] @ w2cat[:, same]^T -> bf16 [2][M][512]
  gemm_kernel<64, 256, 64, 4096, 2, 512, 158, 2, 1, 3, 4, false>
      <<<dim3(158 * 2, 2), 256, 0, stream>>>(h_b, nullptr, w2cat, nullptr, P);

  gather2_final_kernel<<<NN, 128, 0, stream>>>(P, offs, csr, b2_l, out);
}

// Round 5
// 452.957 us; speedup vs baseline: 1.0543x; 1.0185x over previous
//
#include <hip/hip_runtime.h>
#include <cstdint>
#include <cstddef>

#define DEVINL __device__ __forceinline__

typedef __bf16 bf16x8 __attribute__((ext_vector_type(8)));
typedef float f32x4 __attribute__((ext_vector_type(4)));

static constexpr int NN = 10000;     // nodes
static constexpr int NE = 80000;     // edges
static constexpr int IN_DIM = 1024;
static constexpr int HID = 4096;
static constexpr int OUTD = 256;
static constexpr int M_PAD = 10112;  // 79*128 (also 158*64, 316*32)

// fp32 -> bf16 round-nearest-even
DEVINL unsigned short f2bf(float f) {
  unsigned int u = __builtin_bit_cast(unsigned int, f);
  u += 0x7fffu + ((u >> 16) & 1u);
  return (unsigned short)(u >> 16);
}
DEVINL float bf2f(unsigned short h) {
  unsigned int u = ((unsigned int)h) << 16;
  return __builtin_bit_cast(float, u);
}

// async global->LDS, 16B per lane; LDS dest is wave-uniform base + lane*16
DEVINL void ld_lds16(const void* g, void* l) {
  __builtin_amdgcn_global_load_lds(
      (const __attribute__((address_space(1))) unsigned int*)g,
      (__attribute__((address_space(3))) unsigned int*)l, 16, 0, 0);
}

// ---------------- fused prep: conv_w1 + conv_w2 + x->bf16 + degree count ----------------
static constexpr int PREP_B1 = 8192;
static constexpr int PREP_B2 = PREP_B1 + 2048;
static constexpr int PREP_B3 = PREP_B2 + 10000;
static constexpr int PREP_NB = PREP_B3 + 313;

__global__ __launch_bounds__(256) void prep_kernel(
    const float* __restrict__ W1l, const float* __restrict__ W1r,
    const float* __restrict__ W2l, const float* __restrict__ W2r,
    const float* __restrict__ x, const int* __restrict__ dst,
    unsigned short* __restrict__ w1cat, unsigned short* __restrict__ w2cat,
    unsigned short* __restrict__ x_bf, int* __restrict__ deg) {
  int b = blockIdx.x;
  int t = threadIdx.x;
  if (b < PREP_B1) {  // w1cat [4096][2048]: row n = [W1_l row n | W1_r row n]
    int g = b * 256 + t;
    int n = g >> 9;
    int kg = g & 511;
    const float* s = (kg < 256) ? (W1l + (size_t)n * 1024 + kg * 4)
                                : (W1r + (size_t)n * 1024 + (kg - 256) * 4);
    float4 v = *(const float4*)s;
    ushort4 p = {f2bf(v.x), f2bf(v.y), f2bf(v.z), f2bf(v.w)};
    ((ushort4*)w1cat)[g] = p;
  } else if (b < PREP_B2) {  // w2cat [512][4096]: rows 0..255 = W2_l, 256..511 = W2_r
    int g = (b - PREP_B1) * 256 + t;
    int n = g >> 10;
    int kg = g & 1023;
    const float* s = (n < 256) ? (W2l + (size_t)n * 4096 + kg * 4)
                               : (W2r + (size_t)(n - 256) * 4096 + kg * 4);
    float4 v = *(const float4*)s;
    ushort4 p = {f2bf(v.x), f2bf(v.y), f2bf(v.z), f2bf(v.w)};
    ((ushort4*)w2cat)[g] = p;
  } else if (b < PREP_B3) {  // x -> bf16, [10000][1024]
    int g = (b - PREP_B2) * 256 + t;
    int i = g >> 8;
    int kg = g & 255;
    float4 v = ((const float4*)(x + (size_t)i * IN_DIM))[kg];
    ushort4 p = {f2bf(v.x), f2bf(v.y), f2bf(v.z), f2bf(v.w)};
    ((ushort4*)(x_bf + (size_t)i * IN_DIM))[kg] = p;
  } else {  // degree count
    int e = (b - PREP_B3) * 256 + t;
    if (e < NE) atomicAdd(&deg[dst[e]], 1);
  }
}

// one-block exclusive scan over NN degrees -> offs[0..NN] and cursor copy cur[]
__global__ __launch_bounds__(1024) void scan_kernel(const int* __restrict__ deg,
                                                    int* __restrict__ offs,
                                                    int* __restrict__ cur) {
  __shared__ int part[1024];
  constexpr int NPT = 10;  // 1024*10 = 10240 >= NN
  int t = threadIdx.x;
  int base = t * NPT;
  int s = 0;
  for (int j = 0; j < NPT; ++j) {
    int n = base + j;
    s += (n < NN) ? deg[n] : 0;
  }
  part[t] = s;
  __syncthreads();
  for (int o = 1; o < 1024; o <<= 1) {  // Hillis-Steele inclusive scan
    int v = (t >= o) ? part[t - o] : 0;
    __syncthreads();
    part[t] += v;
    __syncthreads();
  }
  int pre = (t > 0) ? part[t - 1] : 0;
  for (int j = 0; j < NPT; ++j) {
    int n = base + j;
    if (n < NN) {
      offs[n] = pre;
      cur[n] = pre;
      pre += deg[n];
    }
  }
  if (t == 1023) offs[NN] = part[1023];  // == NE
}

// bin edges: csr[cur[dst]++] = src  (cur pre-seeded with offs by scan)
__global__ void bin_kernel(const int* __restrict__ src, const int* __restrict__ dst,
                           int* __restrict__ cur, int* __restrict__ csr) {
  int e = blockIdx.x * 256 + threadIdx.x;
  if (e < NE) {
    int p = atomicAdd(&cur[dst[e]], 1);
    csr[p] = src[e];
  }
}

// ---------------- layer-1 gather (bf16 source): A1 = mean_agg(x) only ----------------
// GEMM1 reads x_bf directly for the K>=1024 half, so no x copy here.
// grid = M_PAD blocks; blocks >= NN zero the A1 AND x_bf pad rows.
__global__ __launch_bounds__(256) void gather1_kernel(unsigned short* __restrict__ x_bf,
                                                      const int* __restrict__ offs,
                                                      const int* __restrict__ csr,
                                                      unsigned short* __restrict__ A1) {
  int i = blockIdx.x;
  int t = threadIdx.x;  // 256 threads x ushort4 = 1024 bf16 = one row
  unsigned short* row = A1 + (size_t)i * 1024;
  if (i >= NN) {
    ushort4 z = {0, 0, 0, 0};
    ((ushort4*)row)[t] = z;
    ((ushort4*)(x_bf + (size_t)i * 1024))[t] = z;
    return;
  }
  int beg = offs[i], end = offs[i + 1];
  float4 a0 = {0.f, 0.f, 0.f, 0.f}, a1 = {0.f, 0.f, 0.f, 0.f};
  int j = beg;
  for (; j + 2 <= end; j += 2) {
    int s0 = __builtin_amdgcn_readfirstlane(csr[j]);
    int s1 = __builtin_amdgcn_readfirstlane(csr[j + 1]);
    ushort4 u0 = ((const ushort4*)(x_bf + (size_t)s0 * IN_DIM))[t];
    ushort4 u1 = ((const ushort4*)(x_bf + (size_t)s1 * IN_DIM))[t];
    a0.x += bf2f(u0.x); a0.y += bf2f(u0.y); a0.z += bf2f(u0.z); a0.w += bf2f(u0.w);
    a1.x += bf2f(u1.x); a1.y += bf2f(u1.y); a1.z += bf2f(u1.z); a1.w += bf2f(u1.w);
  }
  if (j < end) {
    int s0 = __builtin_amdgcn_readfirstlane(csr[j]);
    ushort4 u0 = ((const ushort4*)(x_bf + (size_t)s0 * IN_DIM))[t];
    a0.x += bf2f(u0.x); a0.y += bf2f(u0.y); a0.z += bf2f(u0.z); a0.w += bf2f(u0.w);
  }
  float inv = 1.0f / (float)max(end - beg, 1);
  ushort4 pa = {f2bf((a0.x + a1.x) * inv), f2bf((a0.y + a1.y) * inv),
                f2bf((a0.z + a1.z) * inv), f2bf((a0.w + a1.w) * inv)};
  ((ushort4*)row)[t] = pa;
}

// ---------------- bf16 MFMA GEMM, templated BM/BN/BK/split-K/wave-layout ----------------
// C[M_PAD,N] = A[M_PAD,K] * Bt[N,K]^T. 4 waves; NWY = waves along n:
//   NWY=2 -> 2x2 (each wave BM/2 x 64), NWY=4 -> 1x4 (each wave BM x 64, BN=256).
// ASPLIT: A is two [M][K/2] buffers (A for k<K/2, A2 for k>=K/2), both row-stride K/2.
// Block mapping: Triton-style GM-grouped swizzle.
// Split-K: KSPLIT slabs in grid.y, each covers K/KSPLIT; EPI 3 writes bf16 partial.
// LDS chunk swizzle: physical 16B chunk p of row r holds logical chunk p ^ (r&7);
// ds_read_b128 at p=(kk*4+quad)^(l16&7) -> 2-way bank aliasing (free, measured 0 conflicts).
// EPI 1: C0 = bf16 [M][N], relu(acc + bias)             (layer 1)
// EPI 3: C0 = bf16 partial [KSPLIT][M][N] at grid.y     (layer 2, summed in gather2)
// NOTE (R2-R4 session evidence): 256^2 8-wave phase-split reschedules of this GEMM
// measured 242-254 us vs this structure's 233.6 us (MfmaUtil ~30% both) — the 2-phase
// plateau (~700-730 TF) holds for every source-level schedule tried; do not re-roll
// without the full half-tile depth-3 counted-vmcnt pipeline (needs >2 LDS buffers).
template <int BM, int BN, int BK, int K, int KSPLIT, int N, int NUMM, int NUMN, int GM,
          int EPI, int NWY, bool ASPLIT>
__global__ __launch_bounds__(256) void gemm_kernel(const unsigned short* __restrict__ A,
                                                   const unsigned short* __restrict__ A2,
                                                   const unsigned short* __restrict__ Bt,
                                                   const float* __restrict__ bias,
                                                   void* __restrict__ C0out) {
  constexpr int MGR = 4 / NWY;            // waves along m
  constexpr int MI = BM / 16 / MGR;       // 16-row tiles per wave
  constexpr int NI = 4;                   // 16-col tiles per wave (BN = NWY*64)
  constexpr int CPR = BK / 8;             // 16B chunks per LDS row
  constexpr int SA = BM * CPR / 256;      // staging rounds for A (256 thr x 16B)
  constexpr int SB = BN * CPR / 256;
  constexpr int KK = BK / 32;             // MFMA k-steps per tile
  constexpr int KS = K / KSPLIT;          // K range per split
  constexpr int AS = ASPLIT ? K / 2 : K;  // A row stride
  __shared__ unsigned short Asm[BM * BK];
  __shared__ unsigned short Bsm[BN * BK];

  // grouped swizzle on grid.x
  constexpr int NPG = GM * NUMN;
  const int pid = blockIdx.x;
  const int gid = pid / NPG;
  const int first_m = gid * GM;
  const int sz = (NUMM - first_m < GM) ? (NUMM - first_m) : GM;
  const int local = pid % NPG;
  const int pm = first_m + local % sz;
  const int pn = local / sz;
  const int koff = (KSPLIT > 1) ? (int)blockIdx.y * KS : 0;

  const int tid = threadIdx.x;
  const int lane = tid & 63;
  const int wave = tid >> 6;
  const int quad = lane >> 4;
  const int l16 = lane & 15;
  const int wm = (wave % MGR) * (BM / MGR);
  const int wn = (wave / MGR) * 64;
  const long tm0 = (long)pm * BM;
  const long tn0 = (long)pn * BN;

  f32x4 acc[MI][NI];
#pragma unroll
  for (int i = 0; i < MI; ++i)
#pragma unroll
    for (int j = 0; j < NI; ++j) acc[i][j] = (f32x4){0.f, 0.f, 0.f, 0.f};

  // staging: chunk c = s*256 + tid; row r = c / CPR; physical slot = c % CPR;
  // source logical chunk g = slot ^ (r & 7)  -> global col g*8
  size_t aOff[SA];
  unsigned short* aDst[SA];
  const unsigned short* bSrc[SB];
  unsigned short* bDst[SB];
#pragma unroll
  for (int s = 0; s < SA; ++s) {
    int c = s * 256 + wave * 64 + lane;
    int r = c / CPR;
    int g = (c % CPR) ^ (r & 7);
    aOff[s] = (size_t)(tm0 + r) * AS + koff + g * 8;
    aDst[s] = Asm + s * 2048 + wave * 512;  // wave-uniform base
  }
#pragma unroll
  for (int s = 0; s < SB; ++s) {
    int c = s * 256 + wave * 64 + lane;
    int r = c / CPR;
    int g = (c % CPR) ^ (r & 7);
    bSrc[s] = Bt + (size_t)(tn0 + r) * K + koff + g * 8;
    bDst[s] = Bsm + s * 2048 + wave * 512;
  }

  const int l7 = l16 & 7;

  for (int k0 = 0; k0 < KS; k0 += BK) {
    const unsigned short* ab = (!ASPLIT || k0 < K / 2) ? A : A2;
    const int ka = ASPLIT ? (k0 & (K / 2 - 1)) : k0;
#pragma unroll
    for (int s = 0; s < SA; ++s) ld_lds16(ab + aOff[s] + ka, aDst[s]);
#pragma unroll
    for (int s = 0; s < SB; ++s) ld_lds16(bSrc[s] + k0, bDst[s]);
    __syncthreads();  // drains vmcnt -> LDS tiles complete

#pragma unroll
    for (int kk = 0; kk < KK; ++kk) {
      const int p = (kk * 4 + quad) ^ l7;  // physical chunk for this frag
      bf16x8 af[MI], bv[NI];
#pragma unroll
      for (int i = 0; i < MI; ++i) {
        int ra = wm + i * 16 + l16;
        af[i] = *(const bf16x8*)(Asm + ra * BK + p * 8);
      }
#pragma unroll
      for (int j = 0; j < NI; ++j) {
        int rb = wn + j * 16 + l16;
        bv[j] = *(const bf16x8*)(Bsm + rb * BK + p * 8);
      }
#pragma unroll
      for (int i = 0; i < MI; ++i)
#pragma unroll
        for (int j = 0; j < NI; ++j)
          acc[i][j] = __builtin_amdgcn_mfma_f32_16x16x32_bf16(af[i], bv[j], acc[i][j], 0, 0, 0);
    }
    __syncthreads();  // LDS reads done before next stage overwrites
  }

  // epilogue: C/D layout col = lane&15, row = quad*4 + reg
  if (EPI == 1) {
    unsigned short* C = (unsigned short*)C0out;
#pragma unroll
    for (int i = 0; i < MI; ++i) {
      long m0 = tm0 + wm + i * 16 + quad * 4;
#pragma unroll
      for (int j = 0; j < NI; ++j) {
        int n = (int)tn0 + wn + j * 16 + l16;
        float bvs = bias[n];
#pragma unroll
        for (int r = 0; r < 4; ++r) {
          float v = acc[i][j][r] + bvs;
          v = fmaxf(v, 0.0f);
          C[(size_t)(m0 + r) * N + n] = f2bf(v);
        }
      }
    }
  } else {  // EPI == 3: bf16 partial, slab per grid.y
    unsigned short* C = (unsigned short*)C0out + (size_t)blockIdx.y * NUMM * BM * N;
#pragma unroll
    for (int i = 0; i < MI; ++i) {
      long m0 = tm0 + wm + i * 16 + quad * 4;
#pragma unroll
      for (int j = 0; j < NI; ++j) {
        int n = (int)tn0 + wn + j * 16 + l16;
#pragma unroll
        for (int r = 0; r < 4; ++r) C[(size_t)(m0 + r) * N + n] = f2bf(acc[i][j][r]);
      }
    }
  }
}

// ---------------- layer-2 gather + bias + p_r + log_softmax (fused, reads split-K P) ----
// P = [2][M_PAD][512] bf16 (cols 0..255 = p_l partial, 256..511 = p_r partial).
// 128 threads/block, thread t owns cols {2t, 2t+1}; edge loop x2 unrolled (4 loads in flight).
__global__ __launch_bounds__(128) void gather2_final_kernel(const unsigned short* __restrict__ P,
                                                            const int* __restrict__ offs,
                                                            const int* __restrict__ csr,
                                                            const float* __restrict__ b2,
                                                            float* __restrict__ out) {
  int i = blockIdx.x;
  int t = threadIdx.x;  // 0..127
  const unsigned short* P1 = P + (size_t)M_PAD * 512;
  int beg = offs[i], end = offs[i + 1];
  float a0 = 0.f, a1 = 0.f, c0 = 0.f, c1 = 0.f;
  int j = beg;
  for (; j + 2 <= end; j += 2) {
    int s0 = __builtin_amdgcn_readfirstlane(csr[j]);
    int s1 = __builtin_amdgcn_readfirstlane(csr[j + 1]);
    unsigned int u0 = ((const unsigned int*)(P + (size_t)s0 * 512))[t];
    unsigned int w0 = ((const unsigned int*)(P1 + (size_t)s0 * 512))[t];
    unsigned int u1 = ((const unsigned int*)(P + (size_t)s1 * 512))[t];
    unsigned int w1 = ((const unsigned int*)(P1 + (size_t)s1 * 512))[t];
    a0 += bf2f((unsigned short)(u0 & 0xffffu)) + bf2f((unsigned short)(w0 & 0xffffu));
    a1 += bf2f((unsigned short)(u0 >> 16)) + bf2f((unsigned short)(w0 >> 16));
    c0 += bf2f((unsigned short)(u1 & 0xffffu)) + bf2f((unsigned short)(w1 & 0xffffu));
    c1 += bf2f((unsigned short)(u1 >> 16)) + bf2f((unsigned short)(w1 >> 16));
  }
  if (j < end) {
    int s0 = __builtin_amdgcn_readfirstlane(csr[j]);
    unsigned int u0 = ((const unsigned int*)(P + (size_t)s0 * 512))[t];
    unsigned int w0 = ((const unsigned int*)(P1 + (size_t)s0 * 512))[t];
    a0 += bf2f((unsigned short)(u0 & 0xffffu)) + bf2f((unsigned short)(w0 & 0xffffu));
    a1 += bf2f((unsigned short)(u0 >> 16)) + bf2f((unsigned short)(w0 >> 16));
  }
  float inv = 1.0f / (float)max(end - beg, 1);
  float2 bv = ((const float2*)b2)[t];
  // self p_r term: cols 256+2t, 257+2t of both partial slabs
  unsigned int su = ((const unsigned int*)(P + (size_t)i * 512))[128 + t];
  unsigned int sw = ((const unsigned int*)(P1 + (size_t)i * 512))[128 + t];
  float pv0 = bf2f((unsigned short)(su & 0xffffu)) + bf2f((unsigned short)(sw & 0xffffu));
  float pv1 = bf2f((unsigned short)(su >> 16)) + bf2f((unsigned short)(sw >> 16));
  float v0 = (a0 + c0) * inv + bv.x + pv0;
  float v1 = (a1 + c1) * inv + bv.y + pv1;

  __shared__ float sm[2], ss[2];
  int w = t >> 6;
  float m = fmaxf(v0, v1);
#pragma unroll
  for (int o = 32; o > 0; o >>= 1) m = fmaxf(m, __shfl_xor(m, o, 64));
  if ((t & 63) == 0) sm[w] = m;
  __syncthreads();
  m = fmaxf(sm[0], sm[1]);

  float s = __expf(v0 - m) + __expf(v1 - m);
#pragma unroll
  for (int o = 32; o > 0; o >>= 1) s += __shfl_xor(s, o, 64);
  if ((t & 63) == 0) ss[w] = s;
  __syncthreads();
  float ls = logf(ss[0] + ss[1]);

  float2 o2 = {v0 - m - ls, v1 - m - ls};
  ((float2*)(out + (size_t)i * OUTD))[t] = o2;
}

// ---------------- workspace layout (bytes) ----------------
// A1 mean [10112][1024] bf16 = 20.7 MB   (after GEMM1: reused as P [2][10112][512] bf16)
// x_bf    [10112][1024] bf16 = 20.7 MB   (read by gather1 AND by GEMM1's K>=1024 half)
// w1cat [4096][2048] bf16 = 16.8 MB | h_b [10112][4096] bf16 = 82.8 MB | w2cat 4.2 MB
static constexpr size_t OFF_A1 = 0;
static constexpr size_t OFF_XBF = OFF_A1 + (size_t)M_PAD * 1024 * 2;
static constexpr size_t OFF_W1 = OFF_XBF + (size_t)M_PAD * 1024 * 2;
static constexpr size_t OFF_HB = OFF_W1 + (size_t)HID * 2048 * 2;
static constexpr size_t OFF_W2 = OFF_HB + (size_t)M_PAD * HID * 2;
static constexpr size_t OFF_DEG = OFF_W2 + (size_t)512 * HID * 2;
static constexpr size_t OFF_OFFS = OFF_DEG + (size_t)NN * 4;
static constexpr size_t OFF_CUR = OFF_OFFS + (size_t)(NN + 4) * 4;
static constexpr size_t OFF_CSR = OFF_CUR + (size_t)NN * 4;
static constexpr size_t OFF_P = OFF_A1;  // [2][M_PAD][512] bf16 = 20.7 MB, fits A1 region

extern "C" void kernel_launch(void* const* d_in, const int* in_sizes, int n_in,
                              void* d_out, int out_size, void* d_ws, size_t ws_size,
                              hipStream_t stream) {
  const float* x = (const float*)d_in[0];
  const int* ei = (const int*)d_in[1];
  const int* src = ei;
  const int* dst = ei + NE;
  const float* W1_l = (const float*)d_in[2];
  const float* b1_l = (const float*)d_in[3];
  const float* W1_r = (const float*)d_in[4];
  const float* W2_l = (const float*)d_in[5];
  const float* b2_l = (const float*)d_in[6];
  const float* W2_r = (const float*)d_in[7];
  float* out = (float*)d_out;

  char* ws = (char*)d_ws;
  unsigned short* A1 = (unsigned short*)(ws + OFF_A1);
  unsigned short* x_bf = (unsigned short*)(ws + OFF_XBF);
  unsigned short* w1cat = (unsigned short*)(ws + OFF_W1);
  unsigned short* h_b = (unsigned short*)(ws + OFF_HB);
  unsigned short* w2cat = (unsigned short*)(ws + OFF_W2);
  int* deg = (int*)(ws + OFF_DEG);
  int* offs = (int*)(ws + OFF_OFFS);
  int* cur = (int*)(ws + OFF_CUR);
  int* csr = (int*)(ws + OFF_CSR);
  unsigned short* P = (unsigned short*)(ws + OFF_P);

  // zero degree counters (ws is poisoned 0xAA before every call)
  hipMemsetAsync(deg, 0, (size_t)NN * 4, stream);

  // fused prep: weight converts + x->bf16 + degree count
  prep_kernel<<<PREP_NB, 256, 0, stream>>>(W1_l, W1_r, W2_l, W2_r, x, dst,
                                           w1cat, w2cat, x_bf, deg);
  scan_kernel<<<1, 1024, 0, stream>>>(deg, offs, cur);
  bin_kernel<<<(NE + 255) / 256, 256, 0, stream>>>(src, dst, cur, csr);

  // A1 = mean agg (bf16) via CSR gather; pad rows of A1 AND x_bf zeroed here
  gather1_kernel<<<M_PAD, 256, 0, stream>>>(x_bf, offs, csr, A1);

  // h = relu([A1 | x_bf] @ w1cat^T + b1) -> bf16 [10112][4096]; verified 128^2 baseline
  gemm_kernel<128, 128, 64, 2048, 1, 4096, 79, 32, 32, 1, 2, true>
      <<<79 * 32, 256, 0, stream>>>(A1, x_bf, w1cat, b1_l, h_b);

  // split-K=2, BM=32: P[s] = h[:, s*2048:(s+1)*2048] @ w2cat[:, same]^T -> bf16 [2][M][512]
  // BM 64->32 (NUMM 158->316): grid 632->1264 blocks = 4.94 rounds on 256 CUs (was 2.47
  // rounds, ~18% tail idle). P slab layout (NUMM*BM*N) unchanged -> gather2 untouched.
  gemm_kernel<32, 256, 64, 4096, 2, 512, 316, 2, 1, 3, 4, false>
      <<<dim3(316 * 2, 2), 256, 0, stream>>>(h_b, nullptr, w2cat, nullptr, P);

  // mean of p_l over in-edges + bias + p_r (both summed from split-K partials), log_softmax
  gather2_final_kernel<<<NN, 128, 0, stream>>>(P, offs, csr, b2_l, out);
}

// Round 6
// 441.658 us; speedup vs baseline: 1.0813x; 1.0256x over previous
//
#include <hip/hip_runtime.h>
#include <cstdint>
#include <cstddef>

#define DEVINL __device__ __forceinline__

typedef __bf16 bf16x8 __attribute__((ext_vector_type(8)));
typedef float f32x4 __attribute__((ext_vector_type(4)));

static constexpr int NN = 10000;     // nodes
static constexpr int NE = 80000;     // edges
static constexpr int IN_DIM = 1024;
static constexpr int HID = 4096;
static constexpr int OUTD = 256;
static constexpr int M_PAD = 10112;  // 79*128 (also 158*64)

// fp32 -> bf16 round-nearest-even
DEVINL unsigned short f2bf(float f) {
  unsigned int u = __builtin_bit_cast(unsigned int, f);
  u += 0x7fffu + ((u >> 16) & 1u);
  return (unsigned short)(u >> 16);
}
DEVINL float bf2f(unsigned short h) {
  unsigned int u = ((unsigned int)h) << 16;
  return __builtin_bit_cast(float, u);
}

// async global->LDS, 16B per lane; LDS dest is wave-uniform base + lane*16
DEVINL void ld_lds16(const void* g, void* l) {
  __builtin_amdgcn_global_load_lds(
      (const __attribute__((address_space(1))) unsigned int*)g,
      (__attribute__((address_space(3))) unsigned int*)l, 16, 0, 0);
}

// ---------------- fused prep: conv_w1 + conv_w2 + x->bf16 + degree count ----------------
static constexpr int PREP_B1 = 8192;
static constexpr int PREP_B2 = PREP_B1 + 2048;
static constexpr int PREP_B3 = PREP_B2 + 10000;
static constexpr int PREP_NB = PREP_B3 + 313;

__global__ __launch_bounds__(256) void prep_kernel(
    const float* __restrict__ W1l, const float* __restrict__ W1r,
    const float* __restrict__ W2l, const float* __restrict__ W2r,
    const float* __restrict__ x, const int* __restrict__ dst,
    unsigned short* __restrict__ w1cat, unsigned short* __restrict__ w2cat,
    unsigned short* __restrict__ x_bf, int* __restrict__ deg) {
  int b = blockIdx.x;
  int t = threadIdx.x;
  if (b < PREP_B1) {  // w1cat [4096][2048]: row n = [W1_l row n | W1_r row n]
    int g = b * 256 + t;
    int n = g >> 9;
    int kg = g & 511;
    const float* s = (kg < 256) ? (W1l + (size_t)n * 1024 + kg * 4)
                                : (W1r + (size_t)n * 1024 + (kg - 256) * 4);
    float4 v = *(const float4*)s;
    ushort4 p = {f2bf(v.x), f2bf(v.y), f2bf(v.z), f2bf(v.w)};
    ((ushort4*)w1cat)[g] = p;
  } else if (b < PREP_B2) {  // w2cat [512][4096]: rows 0..255 = W2_l, 256..511 = W2_r
    int g = (b - PREP_B1) * 256 + t;
    int n = g >> 10;
    int kg = g & 1023;
    const float* s = (n < 256) ? (W2l + (size_t)n * 4096 + kg * 4)
                               : (W2r + (size_t)(n - 256) * 4096 + kg * 4);
    float4 v = *(const float4*)s;
    ushort4 p = {f2bf(v.x), f2bf(v.y), f2bf(v.z), f2bf(v.w)};
    ((ushort4*)w2cat)[g] = p;
  } else if (b < PREP_B3) {  // x -> bf16, [10000][1024]
    int g = (b - PREP_B2) * 256 + t;
    int i = g >> 8;
    int kg = g & 255;
    float4 v = ((const float4*)(x + (size_t)i * IN_DIM))[kg];
    ushort4 p = {f2bf(v.x), f2bf(v.y), f2bf(v.z), f2bf(v.w)};
    ((ushort4*)(x_bf + (size_t)i * IN_DIM))[kg] = p;
  } else {  // degree count
    int e = (b - PREP_B3) * 256 + t;
    if (e < NE) atomicAdd(&deg[dst[e]], 1);
  }
}

// one-block exclusive scan over NN degrees -> offs[0..NN] and cursor copy cur[]
__global__ __launch_bounds__(1024) void scan_kernel(const int* __restrict__ deg,
                                                    int* __restrict__ offs,
                                                    int* __restrict__ cur) {
  __shared__ int part[1024];
  constexpr int NPT = 10;  // 1024*10 = 10240 >= NN
  int t = threadIdx.x;
  int base = t * NPT;
  int s = 0;
  for (int j = 0; j < NPT; ++j) {
    int n = base + j;
    s += (n < NN) ? deg[n] : 0;
  }
  part[t] = s;
  __syncthreads();
  for (int o = 1; o < 1024; o <<= 1) {  // Hillis-Steele inclusive scan
    int v = (t >= o) ? part[t - o] : 0;
    __syncthreads();
    part[t] += v;
    __syncthreads();
  }
  int pre = (t > 0) ? part[t - 1] : 0;
  for (int j = 0; j < NPT; ++j) {
    int n = base + j;
    if (n < NN) {
      offs[n] = pre;
      cur[n] = pre;
      pre += deg[n];
    }
  }
  if (t == 1023) offs[NN] = part[1023];  // == NE
}

// bin edges: csr[cur[dst]++] = src  (cur pre-seeded with offs by scan)
__global__ void bin_kernel(const int* __restrict__ src, const int* __restrict__ dst,
                           int* __restrict__ cur, int* __restrict__ csr) {
  int e = blockIdx.x * 256 + threadIdx.x;
  if (e < NE) {
    int p = atomicAdd(&cur[dst[e]], 1);
    csr[p] = src[e];
  }
}

// ---------------- layer-1 gather (bf16 source): A1 = mean_agg(x) only ----------------
__global__ __launch_bounds__(256) void gather1_kernel(unsigned short* __restrict__ x_bf,
                                                      const int* __restrict__ offs,
                                                      const int* __restrict__ csr,
                                                      unsigned short* __restrict__ A1) {
  int i = blockIdx.x;
  int t = threadIdx.x;  // 256 threads x ushort4 = 1024 bf16 = one row
  unsigned short* row = A1 + (size_t)i * 1024;
  if (i >= NN) {
    ushort4 z = {0, 0, 0, 0};
    ((ushort4*)row)[t] = z;
    ((ushort4*)(x_bf + (size_t)i * 1024))[t] = z;
    return;
  }
  int beg = offs[i], end = offs[i + 1];
  float4 a0 = {0.f, 0.f, 0.f, 0.f}, a1 = {0.f, 0.f, 0.f, 0.f};
  int j = beg;
  for (; j + 2 <= end; j += 2) {
    int s0 = __builtin_amdgcn_readfirstlane(csr[j]);
    int s1 = __builtin_amdgcn_readfirstlane(csr[j + 1]);
    ushort4 u0 = ((const ushort4*)(x_bf + (size_t)s0 * IN_DIM))[t];
    ushort4 u1 = ((const ushort4*)(x_bf + (size_t)s1 * IN_DIM))[t];
    a0.x += bf2f(u0.x); a0.y += bf2f(u0.y); a0.z += bf2f(u0.z); a0.w += bf2f(u0.w);
    a1.x += bf2f(u1.x); a1.y += bf2f(u1.y); a1.z += bf2f(u1.z); a1.w += bf2f(u1.w);
  }
  if (j < end) {
    int s0 = __builtin_amdgcn_readfirstlane(csr[j]);
    ushort4 u0 = ((const ushort4*)(x_bf + (size_t)s0 * IN_DIM))[t];
    a0.x += bf2f(u0.x); a0.y += bf2f(u0.y); a0.z += bf2f(u0.z); a0.w += bf2f(u0.w);
  }
  float inv = 1.0f / (float)max(end - beg, 1);
  ushort4 pa = {f2bf((a0.x + a1.x) * inv), f2bf((a0.y + a1.y) * inv),
                f2bf((a0.z + a1.z) * inv), f2bf((a0.w + a1.w) * inv)};
  ((ushort4*)row)[t] = pa;
}

// ---------------- GEMM1: 128x128 baseline geometry + counted-vmcnt deep pipeline --------
// Identical tile/wave/staging/swizzle/inner-loop to the verified 128^2 kernel; the ONLY
// change is the staging schedule (T4): A double-buffered (prefetch distance 1, L2-warm
// panel), B TRIPLE-buffered (distance 2, covers HBM latency). LDS 80KB -> 2 blocks/CU
// (preserves baseline co-residency, unlike the 256^2 attempts that dropped to 1).
// Per wave per tile: 4 A-loads then 4 B-loads (fixed issue order). Steady-state wait is
// s_waitcnt vmcnt(12): newest 12 = B(t+2),A(t+1),B(t+1) stay IN FLIGHT across barriers;
// everything older (A(t),B(t),...) is forced complete. Never drains to 0 mid-loop.
// Raw s_barrier (no implicit vmcnt/lgkm drain); vmcnt BEFORE barrier so the barrier
// publishes "all waves' tile-t loads landed". Hazards: stage at iter t writes the buffer
// consumed at iter t-1, issued after t-1's closing barrier (reads all consumed).
__global__ __launch_bounds__(256) void gemm1_pipe_kernel(
    const unsigned short* __restrict__ A,    // A1  (k < 1024), row stride 1024
    const unsigned short* __restrict__ A2,   // x_bf (k >= 1024), row stride 1024
    const unsigned short* __restrict__ Bt,   // w1cat [4096][2048]
    const float* __restrict__ bias,
    unsigned short* __restrict__ C) {
  constexpr int BM = 128, BN = 128, BK = 64;
  constexpr int K = 2048, N = 4096;
  constexpr int NT = K / BK;  // 32
  constexpr int NUMM = 79, NUMN = 32, GM = 32, NPG = GM * NUMN;
  constexpr int TSZ = BM * BK;  // 8192 bf16 = 16KB

  __shared__ unsigned short Asm[2 * TSZ];  // 32KB
  __shared__ unsigned short Bsm[3 * TSZ];  // 48KB  (total 80KB -> 2 blocks/CU)

  // grouped swizzle on grid.x (identical to baseline)
  const int pid = blockIdx.x;
  const int gid = pid / NPG;
  const int first_m = gid * GM;
  const int sz = (NUMM - first_m < GM) ? (NUMM - first_m) : GM;
  const int local = pid % NPG;
  const int pm = first_m + local % sz;
  const int pn = local / sz;
  const long tm0 = (long)pm * BM;
  const long tn0 = (long)pn * BN;

  const int tid = threadIdx.x;
  const int lane = tid & 63;
  const int wave = tid >> 6;
  const int quad = lane >> 4;
  const int l16 = lane & 15;
  const int l7 = l16 & 7;
  const int wm = (wave % 2) * 64;  // 2x2 wave layout, as baseline
  const int wn = (wave / 2) * 64;

  f32x4 acc[4][4];
#pragma unroll
  for (int i = 0; i < 4; ++i)
#pragma unroll
    for (int j = 0; j < 4; ++j) acc[i][j] = (f32x4){0.f, 0.f, 0.f, 0.f};

  // staging map (identical): chunk c = s*256 + tid; row r = c/8; slot = c%8;
  // source logical chunk g = slot ^ (r&7); LDS dest linear (wave-uniform + lane*16)
  size_t aOff[4], bOff[4];
#pragma unroll
  for (int s = 0; s < 4; ++s) {
    int c = s * 256 + tid;
    int r = c >> 3;
    int g = (c & 7) ^ (r & 7);
    aOff[s] = (size_t)(tm0 + r) * 1024 + g * 8;  // A row stride = K/2 = 1024 (ASPLIT)
    bOff[s] = (size_t)(tn0 + r) * K + g * 8;
  }

#define STAGE_A1(kt, ab)                                                            \
  {                                                                                 \
    const unsigned short* s_ = ((kt) < NT / 2) ? A : A2;                            \
    const int ka_ = ((kt) & (NT / 2 - 1)) * BK;                                     \
    _Pragma("unroll") for (int q_ = 0; q_ < 4; ++q_)                                \
        ld_lds16(s_ + aOff[q_] + ka_, Asm + (ab)*TSZ + q_ * 2048 + wave * 512);     \
  }
#define STAGE_B1(kt, bb)                                                            \
  {                                                                                 \
    const int k0_ = (kt)*BK;                                                        \
    _Pragma("unroll") for (int q_ = 0; q_ < 4; ++q_)                                \
        ld_lds16(Bt + bOff[q_] + k0_, Bsm + (bb)*TSZ + q_ * 2048 + wave * 512);     \
  }

  // prologue: A(0); B(0); B(1)  (B runs 2 ahead, A 1 ahead)
  STAGE_A1(0, 0)
  STAGE_B1(0, 0)
  STAGE_B1(1, 1)

  int bb = 0;  // t % 3
  for (int t = 0; t < NT; ++t) {
    // issue next stages FIRST (they target buffers whose reads finished at iter t-1)
    if (t + 1 < NT) STAGE_A1(t + 1, (t + 1) & 1)
    if (t + 2 < NT) {
      int bb2 = bb + 2;
      if (bb2 >= 3) bb2 -= 3;
      STAGE_B1(t + 2, bb2)
    }
    // counted wait: force tile t's loads complete, keep newer 12 (8 at tail) in flight
    if (t + 2 < NT) {
      asm volatile("s_waitcnt vmcnt(12)" ::: "memory");
    } else if (t + 1 < NT) {
      asm volatile("s_waitcnt vmcnt(8)" ::: "memory");
    } else {
      asm volatile("s_waitcnt vmcnt(0)" ::: "memory");
    }
    __builtin_amdgcn_s_barrier();          // raw: loads for t landed in ALL waves
    __builtin_amdgcn_sched_barrier(0);     // keep ds_reads below the barrier

    const unsigned short* As = Asm + (t & 1) * TSZ;
    const unsigned short* Bs = Bsm + bb * TSZ;
#pragma unroll
    for (int kk = 0; kk < 2; ++kk) {
      const int p = (kk * 4 + quad) ^ l7;
      bf16x8 af[4], bv[4];
#pragma unroll
      for (int i = 0; i < 4; ++i) af[i] = *(const bf16x8*)(As + (wm + i * 16 + l16) * BK + p * 8);
#pragma unroll
      for (int j = 0; j < 4; ++j) bv[j] = *(const bf16x8*)(Bs + (wn + j * 16 + l16) * BK + p * 8);
#pragma unroll
      for (int i = 0; i < 4; ++i)
#pragma unroll
        for (int j = 0; j < 4; ++j)
          acc[i][j] = __builtin_amdgcn_mfma_f32_16x16x32_bf16(af[i], bv[j], acc[i][j], 0, 0, 0);
    }
    __builtin_amdgcn_s_barrier();          // all reads of this tile done before overwrite
    __builtin_amdgcn_sched_barrier(0);
    bb = (bb == 2) ? 0 : bb + 1;
  }
#undef STAGE_A1
#undef STAGE_B1

  // epilogue: relu(acc + bias) -> bf16; C/D layout col = lane&15, row = quad*4 + reg
#pragma unroll
  for (int i = 0; i < 4; ++i) {
    long m0 = tm0 + wm + i * 16 + quad * 4;
#pragma unroll
    for (int j = 0; j < 4; ++j) {
      int n = (int)tn0 + wn + j * 16 + l16;
      float bvs = bias[n];
#pragma unroll
      for (int r = 0; r < 4; ++r) {
        float v = fmaxf(acc[i][j][r] + bvs, 0.0f);
        C[(size_t)(m0 + r) * N + n] = f2bf(v);
      }
    }
  }
}

// ---------------- bf16 MFMA GEMM, templated (kept for GEMM2) ----------------
// NOTE (R5): BM 64->32 for GEMM2 regressed total by ~11-20 us (doubled per-block B
// staging amortization; MI 4->2). Keep BM=64. R2-R4: 256^2 phase-split GEMM1 also
// regressed (242-254 vs 233.6 us). This template is the proven 2-phase structure.
template <int BM, int BN, int BK, int K, int KSPLIT, int N, int NUMM, int NUMN, int GM,
          int EPI, int NWY, bool ASPLIT>
__global__ __launch_bounds__(256) void gemm_kernel(const unsigned short* __restrict__ A,
                                                   const unsigned short* __restrict__ A2,
                                                   const unsigned short* __restrict__ Bt,
                                                   const float* __restrict__ bias,
                                                   void* __restrict__ C0out) {
  constexpr int MGR = 4 / NWY;            // waves along m
  constexpr int MI = BM / 16 / MGR;       // 16-row tiles per wave
  constexpr int NI = 4;                   // 16-col tiles per wave (BN = NWY*64)
  constexpr int CPR = BK / 8;             // 16B chunks per LDS row
  constexpr int SA = BM * CPR / 256;      // staging rounds for A (256 thr x 16B)
  constexpr int SB = BN * CPR / 256;
  constexpr int KK = BK / 32;             // MFMA k-steps per tile
  constexpr int KS = K / KSPLIT;          // K range per split
  constexpr int AS = ASPLIT ? K / 2 : K;  // A row stride
  __shared__ unsigned short Asm[BM * BK];
  __shared__ unsigned short Bsm[BN * BK];

  constexpr int NPG = GM * NUMN;
  const int pid = blockIdx.x;
  const int gid = pid / NPG;
  const int first_m = gid * GM;
  const int sz = (NUMM - first_m < GM) ? (NUMM - first_m) : GM;
  const int local = pid % NPG;
  const int pm = first_m + local % sz;
  const int pn = local / sz;
  const int koff = (KSPLIT > 1) ? (int)blockIdx.y * KS : 0;

  const int tid = threadIdx.x;
  const int lane = tid & 63;
  const int wave = tid >> 6;
  const int quad = lane >> 4;
  const int l16 = lane & 15;
  const int wm = (wave % MGR) * (BM / MGR);
  const int wn = (wave / MGR) * 64;
  const long tm0 = (long)pm * BM;
  const long tn0 = (long)pn * BN;

  f32x4 acc[MI][NI];
#pragma unroll
  for (int i = 0; i < MI; ++i)
#pragma unroll
    for (int j = 0; j < NI; ++j) acc[i][j] = (f32x4){0.f, 0.f, 0.f, 0.f};

  size_t aOff[SA];
  unsigned short* aDst[SA];
  const unsigned short* bSrc[SB];
  unsigned short* bDst[SB];
#pragma unroll
  for (int s = 0; s < SA; ++s) {
    int c = s * 256 + wave * 64 + lane;
    int r = c / CPR;
    int g = (c % CPR) ^ (r & 7);
    aOff[s] = (size_t)(tm0 + r) * AS + koff + g * 8;
    aDst[s] = Asm + s * 2048 + wave * 512;  // wave-uniform base
  }
#pragma unroll
  for (int s = 0; s < SB; ++s) {
    int c = s * 256 + wave * 64 + lane;
    int r = c / CPR;
    int g = (c % CPR) ^ (r & 7);
    bSrc[s] = Bt + (size_t)(tn0 + r) * K + koff + g * 8;
    bDst[s] = Bsm + s * 2048 + wave * 512;
  }

  const int l7 = l16 & 7;

  for (int k0 = 0; k0 < KS; k0 += BK) {
    const unsigned short* ab = (!ASPLIT || k0 < K / 2) ? A : A2;
    const int ka = ASPLIT ? (k0 & (K / 2 - 1)) : k0;
#pragma unroll
    for (int s = 0; s < SA; ++s) ld_lds16(ab + aOff[s] + ka, aDst[s]);
#pragma unroll
    for (int s = 0; s < SB; ++s) ld_lds16(bSrc[s] + k0, bDst[s]);
    __syncthreads();  // drains vmcnt -> LDS tiles complete

#pragma unroll
    for (int kk = 0; kk < KK; ++kk) {
      const int p = (kk * 4 + quad) ^ l7;  // physical chunk for this frag
      bf16x8 af[MI], bv[NI];
#pragma unroll
      for (int i = 0; i < MI; ++i) {
        int ra = wm + i * 16 + l16;
        af[i] = *(const bf16x8*)(Asm + ra * BK + p * 8);
      }
#pragma unroll
      for (int j = 0; j < NI; ++j) {
        int rb = wn + j * 16 + l16;
        bv[j] = *(const bf16x8*)(Bsm + rb * BK + p * 8);
      }
#pragma unroll
      for (int i = 0; i < MI; ++i)
#pragma unroll
        for (int j = 0; j < NI; ++j)
          acc[i][j] = __builtin_amdgcn_mfma_f32_16x16x32_bf16(af[i], bv[j], acc[i][j], 0, 0, 0);
    }
    __syncthreads();  // LDS reads done before next stage overwrites
  }

  if (EPI == 1) {
    unsigned short* C = (unsigned short*)C0out;
#pragma unroll
    for (int i = 0; i < MI; ++i) {
      long m0 = tm0 + wm + i * 16 + quad * 4;
#pragma unroll
      for (int j = 0; j < NI; ++j) {
        int n = (int)tn0 + wn + j * 16 + l16;
        float bvs = bias[n];
#pragma unroll
        for (int r = 0; r < 4; ++r) {
          float v = acc[i][j][r] + bvs;
          v = fmaxf(v, 0.0f);
          C[(size_t)(m0 + r) * N + n] = f2bf(v);
        }
      }
    }
  } else {  // EPI == 3: bf16 partial, slab per grid.y
    unsigned short* C = (unsigned short*)C0out + (size_t)blockIdx.y * NUMM * BM * N;
#pragma unroll
    for (int i = 0; i < MI; ++i) {
      long m0 = tm0 + wm + i * 16 + quad * 4;
#pragma unroll
      for (int j = 0; j < NI; ++j) {
        int n = (int)tn0 + wn + j * 16 + l16;
#pragma unroll
        for (int r = 0; r < 4; ++r) C[(size_t)(m0 + r) * N + n] = f2bf(acc[i][j][r]);
      }
    }
  }
}

// ---------------- layer-2 gather + bias + p_r + log_softmax (fused, reads split-K P) ----
__global__ __launch_bounds__(128) void gather2_final_kernel(const unsigned short* __restrict__ P,
                                                            const int* __restrict__ offs,
                                                            const int* __restrict__ csr,
                                                            const float* __restrict__ b2,
                                                            float* __restrict__ out) {
  int i = blockIdx.x;
  int t = threadIdx.x;  // 0..127
  const unsigned short* P1 = P + (size_t)M_PAD * 512;
  int beg = offs[i], end = offs[i + 1];
  float a0 = 0.f, a1 = 0.f, c0 = 0.f, c1 = 0.f;
  int j = beg;
  for (; j + 2 <= end; j += 2) {
    int s0 = __builtin_amdgcn_readfirstlane(csr[j]);
    int s1 = __builtin_amdgcn_readfirstlane(csr[j + 1]);
    unsigned int u0 = ((const unsigned int*)(P + (size_t)s0 * 512))[t];
    unsigned int w0 = ((const unsigned int*)(P1 + (size_t)s0 * 512))[t];
    unsigned int u1 = ((const unsigned int*)(P + (size_t)s1 * 512))[t];
    unsigned int w1 = ((const unsigned int*)(P1 + (size_t)s1 * 512))[t];
    a0 += bf2f((unsigned short)(u0 & 0xffffu)) + bf2f((unsigned short)(w0 & 0xffffu));
    a1 += bf2f((unsigned short)(u0 >> 16)) + bf2f((unsigned short)(w0 >> 16));
    c0 += bf2f((unsigned short)(u1 & 0xffffu)) + bf2f((unsigned short)(w1 & 0xffffu));
    c1 += bf2f((unsigned short)(u1 >> 16)) + bf2f((unsigned short)(w1 >> 16));
  }
  if (j < end) {
    int s0 = __builtin_amdgcn_readfirstlane(csr[j]);
    unsigned int u0 = ((const unsigned int*)(P + (size_t)s0 * 512))[t];
    unsigned int w0 = ((const unsigned int*)(P1 + (size_t)s0 * 512))[t];
    a0 += bf2f((unsigned short)(u0 & 0xffffu)) + bf2f((unsigned short)(w0 & 0xffffu));
    a1 += bf2f((unsigned short)(u0 >> 16)) + bf2f((unsigned short)(w0 >> 16));
  }
  float inv = 1.0f / (float)max(end - beg, 1);
  float2 bv = ((const float2*)b2)[t];
  // self p_r term: cols 256+2t, 257+2t of both partial slabs
  unsigned int su = ((const unsigned int*)(P + (size_t)i * 512))[128 + t];
  unsigned int sw = ((const unsigned int*)(P1 + (size_t)i * 512))[128 + t];
  float pv0 = bf2f((unsigned short)(su & 0xffffu)) + bf2f((unsigned short)(sw & 0xffffu));
  float pv1 = bf2f((unsigned short)(su >> 16)) + bf2f((unsigned short)(sw >> 16));
  float v0 = (a0 + c0) * inv + bv.x + pv0;
  float v1 = (a1 + c1) * inv + bv.y + pv1;

  __shared__ float sm[2], ss[2];
  int w = t >> 6;
  float m = fmaxf(v0, v1);
#pragma unroll
  for (int o = 32; o > 0; o >>= 1) m = fmaxf(m, __shfl_xor(m, o, 64));
  if ((t & 63) == 0) sm[w] = m;
  __syncthreads();
  m = fmaxf(sm[0], sm[1]);

  float s = __expf(v0 - m) + __expf(v1 - m);
#pragma unroll
  for (int o = 32; o > 0; o >>= 1) s += __shfl_xor(s, o, 64);
  if ((t & 63) == 0) ss[w] = s;
  __syncthreads();
  float ls = logf(ss[0] + ss[1]);

  float2 o2 = {v0 - m - ls, v1 - m - ls};
  ((float2*)(out + (size_t)i * OUTD))[t] = o2;
}

// ---------------- workspace layout (bytes) ----------------
static constexpr size_t OFF_A1 = 0;
static constexpr size_t OFF_XBF = OFF_A1 + (size_t)M_PAD * 1024 * 2;
static constexpr size_t OFF_W1 = OFF_XBF + (size_t)M_PAD * 1024 * 2;
static constexpr size_t OFF_HB = OFF_W1 + (size_t)HID * 2048 * 2;
static constexpr size_t OFF_W2 = OFF_HB + (size_t)M_PAD * HID * 2;
static constexpr size_t OFF_DEG = OFF_W2 + (size_t)512 * HID * 2;
static constexpr size_t OFF_OFFS = OFF_DEG + (size_t)NN * 4;
static constexpr size_t OFF_CUR = OFF_OFFS + (size_t)(NN + 4) * 4;
static constexpr size_t OFF_CSR = OFF_CUR + (size_t)NN * 4;
static constexpr size_t OFF_P = OFF_A1;  // [2][M_PAD][512] bf16 = 20.7 MB, fits A1 region

extern "C" void kernel_launch(void* const* d_in, const int* in_sizes, int n_in,
                              void* d_out, int out_size, void* d_ws, size_t ws_size,
                              hipStream_t stream) {
  const float* x = (const float*)d_in[0];
  const int* ei = (const int*)d_in[1];
  const int* src = ei;
  const int* dst = ei + NE;
  const float* W1_l = (const float*)d_in[2];
  const float* b1_l = (const float*)d_in[3];
  const float* W1_r = (const float*)d_in[4];
  const float* W2_l = (const float*)d_in[5];
  const float* b2_l = (const float*)d_in[6];
  const float* W2_r = (const float*)d_in[7];
  float* out = (float*)d_out;

  char* ws = (char*)d_ws;
  unsigned short* A1 = (unsigned short*)(ws + OFF_A1);
  unsigned short* x_bf = (unsigned short*)(ws + OFF_XBF);
  unsigned short* w1cat = (unsigned short*)(ws + OFF_W1);
  unsigned short* h_b = (unsigned short*)(ws + OFF_HB);
  unsigned short* w2cat = (unsigned short*)(ws + OFF_W2);
  int* deg = (int*)(ws + OFF_DEG);
  int* offs = (int*)(ws + OFF_OFFS);
  int* cur = (int*)(ws + OFF_CUR);
  int* csr = (int*)(ws + OFF_CSR);
  unsigned short* P = (unsigned short*)(ws + OFF_P);

  // zero degree counters (ws is poisoned 0xAA before every call)
  hipMemsetAsync(deg, 0, (size_t)NN * 4, stream);

  prep_kernel<<<PREP_NB, 256, 0, stream>>>(W1_l, W1_r, W2_l, W2_r, x, dst,
                                           w1cat, w2cat, x_bf, deg);
  scan_kernel<<<1, 1024, 0, stream>>>(deg, offs, cur);
  bin_kernel<<<(NE + 255) / 256, 256, 0, stream>>>(src, dst, cur, csr);

  gather1_kernel<<<M_PAD, 256, 0, stream>>>(x_bf, offs, csr, A1);

  // h = relu([A1 | x_bf] @ w1cat^T + b1) -> bf16 [10112][4096]
  // baseline 128^2 geometry + counted-vmcnt A-dbuf/B-tribuf pipeline (80KB LDS)
  gemm1_pipe_kernel<<<79 * 32, 256, 0, stream>>>(A1, x_bf, w1cat, b1_l, h_b);

  // split-K=2, BM=64 (reverted to R2-verified config): P[s] -> bf16 [2][M][512]
  gemm_kernel<64, 256, 64, 4096, 2, 512, 158, 2, 1, 3, 4, false>
      <<<dim3(158 * 2, 2), 256, 0, stream>>>(h_b, nullptr, w2cat, nullptr, P);

  gather2_final_kernel<<<NN, 128, 0, stream>>>(P, offs, csr, b2_l, out);
}